// Round 1
// baseline (617.142 us; speedup 1.0000x reference)
//
#include <hip/hip_runtime.h>
#include <hip/hip_bf16.h>

#define ND 8192
#define NZ 4096
#define IN_DIM 256
#define HID 128
#define MIDW 192
#define NP 4            // metapaths
#define NCH 5           // channels (P+1)
#define DEG 32
#define E_D (ND*DEG)    // 262144 edges per drug metapath
#define E_Z (NZ*DEG)    // 131072 edges per disease metapath

typedef __hip_bfloat16 bf16;
typedef __attribute__((ext_vector_type(8))) short s8v;   // 8 x bf16 bits
typedef __attribute__((ext_vector_type(4))) float f4v;

static __device__ __forceinline__ unsigned short f2bf(float x){
  bf16 b = __float2bfloat16(x);
  return *reinterpret_cast<unsigned short*>(&b);
}

// ---------------- CSR build ----------------
__global__ void k_count_deg(const int* __restrict__ src, int* __restrict__ deg, int E, int n){
  int i = blockIdx.x*blockDim.x + threadIdx.x;   // grid sized exactly NP*E/256
  int m = i / E;
  atomicAdd(&deg[m*n + src[i]], 1);
}

__global__ void k_scan(const int* __restrict__ deg, int* __restrict__ off, int n){
  int m = blockIdx.x; int t = threadIdx.x;
  const int* d = deg + (long)m*n;
  int* o = off + (long)m*(n+1);
  __shared__ int buf[256];
  __shared__ int carry;
  if (t==0) carry = 0;
  __syncthreads();
  for (int base=0; base<n; base+=256){
    int v = d[base+t];
    buf[t] = v;
    __syncthreads();
    for (int s=1; s<256; s<<=1){
      int add = (t>=s) ? buf[t-s] : 0;
      __syncthreads();
      buf[t] += add;
      __syncthreads();
    }
    int inc = buf[t];                 // inclusive
    o[base+t] = carry + inc - v;      // exclusive
    __syncthreads();
    if (t==255) carry += inc;
    __syncthreads();
  }
  if (t==0) o[n] = carry;
}

__global__ void k_scatter(const int* __restrict__ src, const int* __restrict__ dst,
                          const int* __restrict__ off, int* __restrict__ cur,
                          int* __restrict__ csr, int E, int n){
  int i = blockIdx.x*blockDim.x + threadIdx.x;
  int m = i / E;
  int s = src[i];
  int pos = atomicAdd(&cur[m*n + s], 1);
  csr[(long)m*E + off[(long)m*(n+1) + s] + pos] = dst[i];
}

// ---------------- misc converts ----------------
__global__ void k_cvt_bf16(const float* __restrict__ in, bf16* __restrict__ out, long count){
  long i = (long)blockIdx.x*blockDim.x + threadIdx.x;
  if (i < count) out[i] = __float2bfloat16(in[i]);
}

// out[b][c][r] = in[b][r][c]  (to bf16, for MFMA B^T operand)
__global__ void k_transpose(const float* __restrict__ in, bf16* __restrict__ out, int rows, int cols){
  int b = blockIdx.z;
  const float* ib = in + (long)b*rows*cols;
  bf16* ob = out + (long)b*rows*cols;
  int total = rows*cols;
  for (int i = blockIdx.x*blockDim.x + threadIdx.x; i < total; i += gridDim.x*blockDim.x){
    int r = i / cols, c = i - r*cols;
    ob[(long)c*rows + r] = __float2bfloat16(ib[i]);
  }
}

__global__ void k_softmax5(const float* __restrict__ wa, float* __restrict__ w){
  if (threadIdx.x==0 && blockIdx.x==0){
    float mx = wa[0];
    for (int i=1;i<NCH;i++) mx = fmaxf(mx, wa[i]);
    float e[NCH], s=0.f;
    for (int i=0;i<NCH;i++){ e[i]=expf(wa[i]-mx); s+=e[i]; }
    for (int i=0;i<NCH;i++) w[i]=e[i]/s;
  }
}

// ---------------- SPMM aggregation: one wave per (metapath, src node) ----------------
__global__ __launch_bounds__(256) void k_agg(const int* __restrict__ csr, const int* __restrict__ off,
    const float* __restrict__ att, const float* __restrict__ feat,
    bf16* __restrict__ aggr, int n, int E){
  int wid = (blockIdx.x*256 + threadIdx.x) >> 6;
  int lane = threadIdx.x & 63;
  int m = wid / n, s = wid - m*n;
  int o0 = off[(long)m*(n+1)+s], o1 = off[(long)m*(n+1)+s+1];
  const int* lst = csr + (long)m*E;
  float a0=0.f,a1=0.f,a2=0.f,a3=0.f;
  for (int i=o0;i<o1;i++){
    int d = lst[i];
    float a = att[(long)m*n + d];                        // gate by DST node
    const float4 v = *(const float4*)(feat + (long)d*IN_DIM + lane*4);
    a0 += a*v.x; a1 += a*v.y; a2 += a*v.z; a3 += a*v.w;
  }
  float inv = 1.0f / fmaxf((float)(o1-o0), 1.0f);
  ushort4 o;
  o.x = f2bf(a0*inv); o.y = f2bf(a1*inv); o.z = f2bf(a2*inv); o.w = f2bf(a3*inv);
  *(ushort4*)(aggr + ((long)(m+1)*n + s)*IN_DIM + lane*4) = o;
}

// ---------------- generic batched bf16 GEMM: C[m] = act(A[m] @ BT[m]^T + bias[m]) ----------------
// A: (nrows,K) rows contiguous, batch stride a_moff (elements). BT: (N,K) per batch.
// out (bf16): adr = m*out_moff + row*out_rstride + col. 64x64 tile, 4 waves, 2x2 frags/wave.
template<bool RELU, bool HAS_SCALE>
__global__ __launch_bounds__(256) void k_gemm(
    const bf16* __restrict__ A, const bf16* __restrict__ BT,
    const float* __restrict__ bias, bf16* __restrict__ out,
    const float* __restrict__ scale,
    int K, int N, long a_moff, long out_rstride, long out_moff)
{
  __shared__ short As[64*40];   // padded stride 40 (80B) vs bank conflicts
  __shared__ short Bs[64*40];
  int t = threadIdx.x;
  int m = blockIdx.z;
  long row0 = (long)blockIdx.x*64;
  int col0 = blockIdx.y*64;
  const short* Ag = (const short*)A + m*a_moff;
  const short* Bg = (const short*)BT + (long)m*N*K;
  int lane = t & 63, wv = t>>6, wr = wv>>1, wc = wv&1;
  int srow = t>>2, ssub = t&3;
  int l15 = lane & 15, kof = (lane>>4)*8;
  f4v acc[2][2] = {};
  for (int kk=0; kk<K; kk+=32){
    __syncthreads();
    *(s8v*)(&As[srow*40 + ssub*8]) = *(const s8v*)(Ag + (row0+srow)*K + kk + ssub*8);
    *(s8v*)(&Bs[srow*40 + ssub*8]) = *(const s8v*)(Bg + (long)(col0+srow)*K + kk + ssub*8);
    __syncthreads();
    s8v a0 = *(const s8v*)(&As[(wr*32      + l15)*40 + kof]);
    s8v a1 = *(const s8v*)(&As[(wr*32 + 16 + l15)*40 + kof]);
    s8v b0 = *(const s8v*)(&Bs[(wc*32      + l15)*40 + kof]);
    s8v b1 = *(const s8v*)(&Bs[(wc*32 + 16 + l15)*40 + kof]);
    acc[0][0] = __builtin_amdgcn_mfma_f32_16x16x32_bf16(a0,b0,acc[0][0],0,0,0);
    acc[0][1] = __builtin_amdgcn_mfma_f32_16x16x32_bf16(a0,b1,acc[0][1],0,0,0);
    acc[1][0] = __builtin_amdgcn_mfma_f32_16x16x32_bf16(a1,b0,acc[1][0],0,0,0);
    acc[1][1] = __builtin_amdgcn_mfma_f32_16x16x32_bf16(a1,b1,acc[1][1],0,0,0);
  }
  float sc = HAS_SCALE ? scale[m] : 1.0f;
  #pragma unroll
  for (int mi=0;mi<2;mi++){
    #pragma unroll
    for (int ni=0;ni<2;ni++){
      int col = col0 + wc*32 + ni*16 + l15;
      float bv = bias ? bias[m*N + col] : 0.f;
      #pragma unroll
      for (int r=0;r<4;r++){
        long row = row0 + wr*32 + mi*16 + (lane>>4)*4 + r;
        float v = acc[mi][ni][r] + bv;
        if (RELU) v = fmaxf(v, 0.f);
        v *= sc;
        out[m*out_moff + row*out_rstride + col] = __float2bfloat16(v);
      }
    }
  }
}

// ---------------- per-node metapath attention (one wave per node) ----------------
__global__ __launch_bounds__(64) void k_attn(
    const bf16* __restrict__ p, const bf16* __restrict__ qk,
    const float* __restrict__ beta, bf16* __restrict__ outf, int n)
{
  int node = blockIdx.x; int t = threadIdx.x;
  __shared__ float pl[NCH*HID], ql[NCH*HID], kl[NCH*HID];
  __shared__ float lg[25], at[25];
  const bf16* pp = p  + (long)node*(NCH*HID);
  const bf16* qq = qk + (long)node*(NCH*HID);
  const bf16* kq = qk + (long)n*(NCH*HID) + (long)node*(NCH*HID);
  for (int i=t; i<NCH*HID; i+=64){
    pl[i] = __bfloat162float(pp[i]);
    ql[i] = __bfloat162float(qq[i]);
    kl[i] = __bfloat162float(kq[i]);
  }
  __syncthreads();
  if (t < 25){
    int mi = t/5, ki = t - 5*(t/5);
    float s = 0.f;
    for (int h=0; h<HID; h++) s += ql[mi*HID+h]*kl[ki*HID+h];
    lg[t] = s;
  }
  __syncthreads();
  if (t < 5){
    float mx = lg[t*5];
    for (int j=1;j<5;j++) mx = fmaxf(mx, lg[t*5+j]);
    float e[5], su=0.f;
    for (int j=0;j<5;j++){ e[j] = expf(lg[t*5+j]-mx); su += e[j]; }
    for (int j=0;j<5;j++) at[t*5+j] = e[j]/su;
  }
  __syncthreads();
  float bt = beta[0];
  for (int i=t; i<NCH*HID; i+=64){
    int mm = i>>7, h = i&127;
    float s = 0.f;
    #pragma unroll
    for (int k2=0;k2<5;k2++) s += at[mm*5+k2]*pl[k2*HID+h];
    outf[(long)node*(NCH*HID) + i] = __float2bfloat16(pl[i] + bt*s);
  }
}

// ---------------- final GEMM: out(ND,NZ) = A(ND,640) @ B(NZ,640)^T, f32 out ----------------
// A is out_d_flat addressed via the (M,ND,HID) view: A[d][m*128+h] = buf[(m*ND+d)*128+h]
__global__ __launch_bounds__(256) void k_gemm_final(
    const bf16* __restrict__ Aout, const bf16* __restrict__ Bb, float* __restrict__ out)
{
  __shared__ short As[128*40];
  __shared__ short Bs[128*40];
  int t = threadIdx.x;
  int lane = t&63, wv=t>>6, wr=wv>>1, wc=wv&1;
  int row0 = blockIdx.x*128, col0 = blockIdx.y*128;
  const short* Ag = (const short*)Aout;
  const short* Bg = (const short*)Bb;
  int l15 = lane&15, kof = (lane>>4)*8;
  f4v acc[4][4] = {};
  for (int kk=0; kk<NCH*HID; kk+=32){
    int mch = kk>>7, h0 = kk&127;
    __syncthreads();
    #pragma unroll
    for (int j=0;j<2;j++){
      int c = t + j*256;
      int row = c>>2, sub = c&3;
      *(s8v*)(&As[row*40 + sub*8]) = *(const s8v*)(Ag + ((long)mch*ND + row0+row)*HID + h0 + sub*8);
      *(s8v*)(&Bs[row*40 + sub*8]) = *(const s8v*)(Bg + (long)(col0+row)*(NCH*HID) + kk + sub*8);
    }
    __syncthreads();
    s8v af[4], bg[4];
    #pragma unroll
    for (int i=0;i<4;i++){
      af[i] = *(const s8v*)(&As[(wr*64 + i*16 + l15)*40 + kof]);
      bg[i] = *(const s8v*)(&Bs[(wc*64 + i*16 + l15)*40 + kof]);
    }
    #pragma unroll
    for (int mi=0;mi<4;mi++)
      #pragma unroll
      for (int ni=0;ni<4;ni++)
        acc[mi][ni] = __builtin_amdgcn_mfma_f32_16x16x32_bf16(af[mi], bg[ni], acc[mi][ni],0,0,0);
  }
  #pragma unroll
  for (int mi=0;mi<4;mi++){
    #pragma unroll
    for (int ni=0;ni<4;ni++){
      int col = col0 + wc*64 + ni*16 + l15;
      #pragma unroll
      for (int r=0;r<4;r++){
        int row = row0 + wr*64 + mi*16 + (lane>>4)*4 + r;
        out[(long)row*NZ + col] = acc[mi][ni][r];
      }
    }
  }
}

extern "C" void kernel_launch(void* const* d_in, const int* in_sizes, int n_in,
                              void* d_out, int out_size, void* d_ws, size_t ws_size,
                              hipStream_t stream)
{
  (void)in_sizes; (void)n_in; (void)out_size;
  const float* feat_d = (const float*)d_in[0];
  const float* feat_z = (const float*)d_in[1];
  const float* att_d  = (const float*)d_in[2];
  const float* att_z  = (const float*)d_in[3];
  const int* src_d = (const int*)d_in[4];
  const int* dst_d = (const int*)d_in[5];
  const int* src_z = (const int*)d_in[6];
  const int* dst_z = (const int*)d_in[7];
  const float* dW1=(const float*)d_in[8];  const float* db1=(const float*)d_in[9];
  const float* dW2=(const float*)d_in[10]; const float* db2=(const float*)d_in[11];
  const float* dW3=(const float*)d_in[12]; const float* db3=(const float*)d_in[13];
  const float* Wq_d=(const float*)d_in[14]; const float* bq_d=(const float*)d_in[15];
  const float* Wk_d=(const float*)d_in[16]; const float* bk_d=(const float*)d_in[17];
  const float* beta_d=(const float*)d_in[18];
  const float* zW1=(const float*)d_in[19]; const float* zb1=(const float*)d_in[20];
  const float* zW2=(const float*)d_in[21]; const float* zb2=(const float*)d_in[22];
  const float* zW3=(const float*)d_in[23]; const float* zb3=(const float*)d_in[24];
  const float* Wq_z=(const float*)d_in[25]; const float* bq_z=(const float*)d_in[26];
  const float* Wk_z=(const float*)d_in[27]; const float* bk_z=(const float*)d_in[28];
  const float* beta_z=(const float*)d_in[29];
  const float* wattn=(const float*)d_in[30];
  const float* Wdec=(const float*)d_in[31]; const float* bdec=(const float*)d_in[32];

  char* ws = (char*)d_ws;
  size_t o = 0;
  auto alloc = [&](size_t bytes)->char*{
    size_t r = (o + 255) & ~(size_t)255;
    o = r + bytes;
    return ws + r;
  };
  bf16* aggr_d = (bf16*)alloc((size_t)NCH*ND*IN_DIM*2);   // later reused as h2_d
  bf16* h1_d   = (bf16*)alloc((size_t)NCH*ND*MIDW*2);     // later reused as out_d
  bf16* pbuf_d = (bf16*)alloc((size_t)ND*NCH*HID*2);
  bf16* qk_d   = (bf16*)alloc((size_t)2*ND*NCH*HID*2);
  bf16* aggr_z = (bf16*)alloc((size_t)NCH*NZ*IN_DIM*2);   // later reused as h2_z
  bf16* h1_z   = (bf16*)alloc((size_t)NCH*NZ*MIDW*2);     // later reused as out_z
  bf16* pbuf_z = (bf16*)alloc((size_t)NZ*NCH*HID*2);
  bf16* qk_z   = (bf16*)alloc((size_t)2*NZ*NCH*HID*2);
  bf16* Bbig   = (bf16*)alloc((size_t)NZ*NCH*HID*2);
  int* csr_d = (int*)alloc((size_t)NP*E_D*4);
  int* csr_z = (int*)alloc((size_t)NP*E_Z*4);
  int* degcur = (int*)alloc((size_t)(NP*ND*2 + NP*NZ*2)*4);
  int* deg_d = degcur;
  int* cur_d = deg_d + NP*ND;
  int* deg_z = cur_d + NP*ND;
  int* cur_z = deg_z + NP*NZ;
  int* off_d = (int*)alloc((size_t)NP*(ND+1)*4);
  int* off_z = (int*)alloc((size_t)NP*(NZ+1)*4);
  bf16* w1t_d = (bf16*)alloc((size_t)NCH*MIDW*IN_DIM*2);
  bf16* w2t_d = (bf16*)alloc((size_t)NCH*MIDW*MIDW*2);
  bf16* w3t_d = (bf16*)alloc((size_t)NCH*HID*MIDW*2);
  bf16* w1t_z = (bf16*)alloc((size_t)NCH*MIDW*IN_DIM*2);
  bf16* w2t_z = (bf16*)alloc((size_t)NCH*MIDW*MIDW*2);
  bf16* w3t_z = (bf16*)alloc((size_t)NCH*HID*MIDW*2);
  bf16* qkw_d = (bf16*)alloc((size_t)2*HID*HID*2);
  bf16* qkw_z = (bf16*)alloc((size_t)2*HID*HID*2);
  bf16* wdect = (bf16*)alloc((size_t)NCH*HID*HID*2);
  float* qkb_d = (float*)alloc((size_t)2*HID*4);
  float* qkb_z = (float*)alloc((size_t)2*HID*4);
  float* wsm   = (float*)alloc((size_t)NCH*4);
  bf16* h2_d = aggr_d;   // safe: aggr dead after layer-1 GEMM
  bf16* out_d = h1_d;    // safe: h1 dead after layer-2 GEMM
  bf16* h2_z = aggr_z;
  bf16* out_z = h1_z;
  if (ws_size < o) return;   // fail visibly rather than corrupt

  // CSR build
  hipMemsetAsync(degcur, 0, (size_t)(NP*ND*2 + NP*NZ*2)*4, stream);
  k_count_deg<<<NP*E_D/256, 256, 0, stream>>>(src_d, deg_d, E_D, ND);
  k_count_deg<<<NP*E_Z/256, 256, 0, stream>>>(src_z, deg_z, E_Z, NZ);
  k_scan<<<NP, 256, 0, stream>>>(deg_d, off_d, ND);
  k_scan<<<NP, 256, 0, stream>>>(deg_z, off_z, NZ);
  k_scatter<<<NP*E_D/256, 256, 0, stream>>>(src_d, dst_d, off_d, cur_d, csr_d, E_D, ND);
  k_scatter<<<NP*E_Z/256, 256, 0, stream>>>(src_z, dst_z, off_z, cur_z, csr_z, E_Z, NZ);
  // aggr channel 0 = raw feat (bf16); channels 1..4 = metapath aggregation
  k_cvt_bf16<<<ND*IN_DIM/256, 256, 0, stream>>>(feat_d, aggr_d, (long)ND*IN_DIM);
  k_cvt_bf16<<<NZ*IN_DIM/256, 256, 0, stream>>>(feat_z, aggr_z, (long)NZ*IN_DIM);
  k_agg<<<NP*ND/4, 256, 0, stream>>>(csr_d, off_d, att_d, feat_d, aggr_d, ND, E_D);
  k_agg<<<NP*NZ/4, 256, 0, stream>>>(csr_z, off_z, att_z, feat_z, aggr_z, NZ, E_Z);
  // weight prep (bf16 transposes), bias packs, channel softmax
  k_transpose<<<dim3(32,1,NCH),256,0,stream>>>(dW1, w1t_d, IN_DIM, MIDW);
  k_transpose<<<dim3(32,1,NCH),256,0,stream>>>(dW2, w2t_d, MIDW, MIDW);
  k_transpose<<<dim3(32,1,NCH),256,0,stream>>>(dW3, w3t_d, MIDW, HID);
  k_transpose<<<dim3(32,1,NCH),256,0,stream>>>(zW1, w1t_z, IN_DIM, MIDW);
  k_transpose<<<dim3(32,1,NCH),256,0,stream>>>(zW2, w2t_z, MIDW, MIDW);
  k_transpose<<<dim3(32,1,NCH),256,0,stream>>>(zW3, w3t_z, MIDW, HID);
  k_transpose<<<dim3(16,1,1),256,0,stream>>>(Wq_d, qkw_d, HID, HID);
  k_transpose<<<dim3(16,1,1),256,0,stream>>>(Wk_d, qkw_d + HID*HID, HID, HID);
  k_transpose<<<dim3(16,1,1),256,0,stream>>>(Wq_z, qkw_z, HID, HID);
  k_transpose<<<dim3(16,1,1),256,0,stream>>>(Wk_z, qkw_z + HID*HID, HID, HID);
  k_transpose<<<dim3(32,1,NCH),256,0,stream>>>(Wdec, wdect, HID, HID);
  hipMemcpyAsync(qkb_d, bq_d, HID*4, hipMemcpyDeviceToDevice, stream);
  hipMemcpyAsync(qkb_d+HID, bk_d, HID*4, hipMemcpyDeviceToDevice, stream);
  hipMemcpyAsync(qkb_z, bq_z, HID*4, hipMemcpyDeviceToDevice, stream);
  hipMemcpyAsync(qkb_z+HID, bk_z, HID*4, hipMemcpyDeviceToDevice, stream);
  k_softmax5<<<1,64,0,stream>>>(wattn, wsm);
  // projector drug: 3-layer MLP, batched over 5 channels
  k_gemm<true,false><<<dim3(ND/64, MIDW/64, NCH),256,0,stream>>>(aggr_d, w1t_d, db1, h1_d, nullptr,
      IN_DIM, MIDW, (long)ND*IN_DIM, (long)MIDW, (long)ND*MIDW);
  k_gemm<true,false><<<dim3(ND/64, MIDW/64, NCH),256,0,stream>>>(h1_d, w2t_d, db2, h2_d, nullptr,
      MIDW, MIDW, (long)ND*MIDW, (long)MIDW, (long)ND*MIDW);
  k_gemm<false,false><<<dim3(ND/64, HID/64, NCH),256,0,stream>>>(h2_d, w3t_d, db3, pbuf_d, nullptr,
      MIDW, HID, (long)ND*MIDW, (long)NCH*HID, (long)HID);       // node-major interleaved (n,M,H)
  k_gemm<false,false><<<dim3(ND*NCH/64, HID/64, 2),256,0,stream>>>(pbuf_d, qkw_d, qkb_d, qk_d, nullptr,
      HID, HID, 0L, (long)HID, (long)ND*NCH*HID);                // batch0=Q, batch1=K
  // projector disease
  k_gemm<true,false><<<dim3(NZ/64, MIDW/64, NCH),256,0,stream>>>(aggr_z, w1t_z, zb1, h1_z, nullptr,
      IN_DIM, MIDW, (long)NZ*IN_DIM, (long)MIDW, (long)NZ*MIDW);
  k_gemm<true,false><<<dim3(NZ/64, MIDW/64, NCH),256,0,stream>>>(h1_z, w2t_z, zb2, h2_z, nullptr,
      MIDW, MIDW, (long)NZ*MIDW, (long)MIDW, (long)NZ*MIDW);
  k_gemm<false,false><<<dim3(NZ/64, HID/64, NCH),256,0,stream>>>(h2_z, w3t_z, zb3, pbuf_z, nullptr,
      MIDW, HID, (long)NZ*MIDW, (long)NCH*HID, (long)HID);
  k_gemm<false,false><<<dim3(NZ*NCH/64, HID/64, 2),256,0,stream>>>(pbuf_z, qkw_z, qkb_z, qk_z, nullptr,
      HID, HID, 0L, (long)HID, (long)NZ*NCH*HID);
  // metapath attention (writes node-major (n,M,H) == the faithful .view buffer)
  k_attn<<<ND, 64, 0, stream>>>(pbuf_d, qk_d, beta_d, out_d, ND);
  k_attn<<<NZ, 64, 0, stream>>>(pbuf_z, qk_z, beta_z, out_z, NZ);
  // decoder: Bbig[z, m*128+h] = w_m * (out_z_view[m] @ Wdec[m] + bdec[m])
  k_gemm<false,true><<<dim3(NZ/64, HID/64, NCH),256,0,stream>>>(out_z, wdect, bdec, Bbig, wsm,
      HID, HID, (long)NZ*HID, (long)NCH*HID, (long)HID);
  // final: out = A(ND,640) @ Bbig(NZ,640)^T
  k_gemm_final<<<dim3(ND/128, NZ/128), 256, 0, stream>>>(out_d, Bbig, (float*)d_out);
}

// Round 2
// 567.725 us; speedup vs baseline: 1.0870x; 1.0870x over previous
//
#include <hip/hip_runtime.h>
#include <hip/hip_bf16.h>

#define ND 8192
#define NZ 4096
#define IN_DIM 256
#define HID 128
#define MIDW 192
#define NP 4            // metapaths
#define NCH 5           // channels (P+1)
#define DEG 32
#define E_D (ND*DEG)
#define E_Z (NZ*DEG)

typedef __hip_bfloat16 bf16;
typedef __attribute__((ext_vector_type(8))) short s8v;
typedef __attribute__((ext_vector_type(4))) float f4v;

static __device__ __forceinline__ uint packbf2(float a, float b){
  bf16 x = __float2bfloat16(a), y = __float2bfloat16(b);
  return (uint)*(unsigned short*)&x | ((uint)*(unsigned short*)&y << 16);
}

// ---------------- CSR build ----------------
__global__ void k_count_deg(const int* __restrict__ src, int* __restrict__ deg, int E, int n){
  int i = blockIdx.x*blockDim.x + threadIdx.x;
  int m = i / E;
  atomicAdd(&deg[m*n + src[i]], 1);
}

__global__ void k_scan(const int* __restrict__ deg, int* __restrict__ off, int n){
  int m = blockIdx.x; int t = threadIdx.x;
  const int* d = deg + (long)m*n;
  int* o = off + (long)m*(n+1);
  __shared__ int buf[256];
  __shared__ int carry;
  if (t==0) carry = 0;
  __syncthreads();
  for (int base=0; base<n; base+=256){
    int v = d[base+t];
    buf[t] = v;
    __syncthreads();
    for (int s=1; s<256; s<<=1){
      int add = (t>=s) ? buf[t-s] : 0;
      __syncthreads();
      buf[t] += add;
      __syncthreads();
    }
    int inc = buf[t];
    o[base+t] = carry + inc - v;
    __syncthreads();
    if (t==255) carry += inc;
    __syncthreads();
  }
  if (t==0) o[n] = carry;
}

__global__ void k_scatter(const int* __restrict__ src, const int* __restrict__ dst,
                          const int* __restrict__ off, int* __restrict__ cur,
                          int* __restrict__ csr, int E, int n){
  int i = blockIdx.x*blockDim.x + threadIdx.x;
  int m = i / E;
  int s = src[i];
  int pos = atomicAdd(&cur[m*n + s], 1);
  csr[(long)m*E + off[(long)m*(n+1) + s] + pos] = dst[i];
}

// ---------------- misc ----------------
__global__ void k_cvt_bf16(const float* __restrict__ in, bf16* __restrict__ out, long count){
  long i = (long)blockIdx.x*blockDim.x + threadIdx.x;
  if (i < count) out[i] = __float2bfloat16(in[i]);
}

__global__ void k_transpose(const float* __restrict__ in, bf16* __restrict__ out, int rows, int cols){
  int b = blockIdx.z;
  const float* ib = in + (long)b*rows*cols;
  bf16* ob = out + (long)b*rows*cols;
  int total = rows*cols;
  for (int i = blockIdx.x*blockDim.x + threadIdx.x; i < total; i += gridDim.x*blockDim.x){
    int r = i / cols, c = i - r*cols;
    ob[(long)c*rows + r] = __float2bfloat16(ib[i]);
  }
}

__global__ void k_softmax5(const float* __restrict__ wa, float* __restrict__ w){
  if (threadIdx.x==0 && blockIdx.x==0){
    float mx = wa[0];
    for (int i=1;i<NCH;i++) mx = fmaxf(mx, wa[i]);
    float e[NCH], s=0.f;
    for (int i=0;i<NCH;i++){ e[i]=expf(wa[i]-mx); s+=e[i]; }
    for (int i=0;i<NCH;i++) w[i]=e[i]/s;
  }
}

// ---------------- aggregation over pre-projected Y (bf16, MIDW=192 wide) ----------------
// h1[m+1][s] = relu( (1/deg) * sum_{edges s->d} Y[m][d] + b1[m+1] )
__global__ __launch_bounds__(256) void k_agg2(const int* __restrict__ csr, const int* __restrict__ off,
    const float* __restrict__ bias, const bf16* __restrict__ Y, bf16* __restrict__ h1,
    int n, int E)
{
  int wid = (blockIdx.x*256 + threadIdx.x) >> 6;
  int lane = threadIdx.x & 63;
  int m = wid / n, s = wid - m*n;
  int o0 = off[(long)m*(n+1)+s], o1 = off[(long)m*(n+1)+s+1];
  const int* lst = csr + (long)m*E;
  const uint* Yb = (const uint*)Y + (long)m*n*96;   // 96 dwords = 192 bf16 per row
  bool hi = lane < 32;
  float a0=0.f,a1=0.f,a2=0.f,a3=0.f;
  int i = o0;
  for (; i+1 < o1; i += 2){
    int d0 = lst[i], d1 = lst[i+1];
    const uint* r0 = Yb + (long)d0*96;
    const uint* r1 = Yb + (long)d1*96;
    uint w00 = r0[lane];
    uint w10 = r1[lane];
    uint w01 = hi ? r0[64+lane] : 0u;
    uint w11 = hi ? r1[64+lane] : 0u;
    a0 += __uint_as_float(w00<<16) + __uint_as_float(w10<<16);
    a1 += __uint_as_float(w00&0xffff0000u) + __uint_as_float(w10&0xffff0000u);
    a2 += __uint_as_float(w01<<16) + __uint_as_float(w11<<16);
    a3 += __uint_as_float(w01&0xffff0000u) + __uint_as_float(w11&0xffff0000u);
  }
  if (i < o1){
    int d0 = lst[i];
    const uint* r0 = Yb + (long)d0*96;
    uint w00 = r0[lane];
    uint w01 = hi ? r0[64+lane] : 0u;
    a0 += __uint_as_float(w00<<16);
    a1 += __uint_as_float(w00&0xffff0000u);
    a2 += __uint_as_float(w01<<16);
    a3 += __uint_as_float(w01&0xffff0000u);
  }
  float inv = 1.0f / fmaxf((float)(o1-o0), 1.0f);
  const float* bb = bias + (m+1)*MIDW;
  float2 b0 = *(const float2*)(bb + 2*lane);
  float v0 = fmaxf(a0*inv + b0.x, 0.f);
  float v1 = fmaxf(a1*inv + b0.y, 0.f);
  uint* hrow = (uint*)((short*)h1 + ((long)(m+1)*n + s)*MIDW);
  hrow[lane] = packbf2(v0, v1);
  if (hi){
    float2 b1v = *(const float2*)(bb + 128 + 2*lane);
    float v2 = fmaxf(a2*inv + b1v.x, 0.f);
    float v3 = fmaxf(a3*inv + b1v.y, 0.f);
    hrow[64+lane] = packbf2(v2, v3);
  }
}

// ---------------- batched bf16 GEMM, 128x64 tile, 4 waves, 2x4 frags/wave ----------------
// C[m] = ((act(A[m] @ BT[m]^T + bias[m])) * scale[m]) * rowsc[m][row]
template<bool RELU, bool HAS_SCALE, bool ROWSC>
__global__ __launch_bounds__(256) void k_gemm(
    const bf16* __restrict__ A, const bf16* __restrict__ BT,
    const float* __restrict__ bias, bf16* __restrict__ out,
    const float* __restrict__ scale, const float* __restrict__ rowsc, long rs_moff,
    int K, int N, long a_moff, long out_rstride, long out_moff)
{
  __shared__ short As[128*40];
  __shared__ short Bs[64*40];
  int t = threadIdx.x;
  int m = blockIdx.z;
  long row0 = (long)blockIdx.x*128;
  int col0 = blockIdx.y*64;
  const short* Ag = (const short*)A + m*a_moff;
  const short* Bg = (const short*)BT + (long)m*N*K;
  int lane = t&63, wv = t>>6;
  int l15 = lane&15, kof = (lane>>4)*8;
  f4v acc[2][4] = {};
  for (int kk=0; kk<K; kk+=32){
    __syncthreads();
    #pragma unroll
    for (int j=0;j<2;j++){
      int c = t + j*256;
      int row = c>>2, sub = c&3;
      *(s8v*)(&As[row*40 + sub*8]) = *(const s8v*)(Ag + (row0+row)*K + kk + sub*8);
    }
    { int row = t>>2, sub = t&3;
      *(s8v*)(&Bs[row*40 + sub*8]) = *(const s8v*)(Bg + (long)(col0+row)*K + kk + sub*8); }
    __syncthreads();
    s8v af[2], bfr[4];
    #pragma unroll
    for (int i2=0;i2<2;i2++) af[i2] = *(const s8v*)(&As[(wv*32 + i2*16 + l15)*40 + kof]);
    #pragma unroll
    for (int j2=0;j2<4;j2++) bfr[j2] = *(const s8v*)(&Bs[(j2*16 + l15)*40 + kof]);
    #pragma unroll
    for (int i2=0;i2<2;i2++)
      #pragma unroll
      for (int j2=0;j2<4;j2++)
        acc[i2][j2] = __builtin_amdgcn_mfma_f32_16x16x32_bf16(af[i2], bfr[j2], acc[i2][j2],0,0,0);
  }
  float sc = HAS_SCALE ? scale[m] : 1.0f;
  #pragma unroll
  for (int i2=0;i2<2;i2++){
    #pragma unroll
    for (int j2=0;j2<4;j2++){
      int col = col0 + j2*16 + l15;
      float bv = bias ? bias[m*N + col] : 0.f;
      #pragma unroll
      for (int r=0;r<4;r++){
        long row = row0 + wv*32 + i2*16 + (lane>>4)*4 + r;
        float v = acc[i2][j2][r] + bv;
        if (RELU) v = fmaxf(v, 0.f);
        v *= sc;
        if (ROWSC) v *= rowsc[m*rs_moff + row];
        out[m*out_moff + row*out_rstride + col] = __float2bfloat16(v);
      }
    }
  }
}

// ---------------- per-node metapath attention (one wave per node) ----------------
// qk layout: row (node*NCH + m), 256 cols: [0:128)=Q, [128:256)=K
__global__ __launch_bounds__(64) void k_attn(
    const bf16* __restrict__ p, const bf16* __restrict__ qk,
    const float* __restrict__ beta, bf16* __restrict__ outf, int n)
{
  int node = blockIdx.x; int t = threadIdx.x;
  __shared__ float pl[NCH*HID], ql[NCH*HID], kl[NCH*HID];
  __shared__ float lg[25], at[25];
  const bf16* pp = p  + (long)node*(NCH*HID);
  const bf16* qrow = qk + (long)node*NCH*256;
  for (int i=t; i<NCH*HID; i+=64){
    int mm = i>>7, h = i&127;
    pl[i] = __bfloat162float(pp[i]);
    ql[i] = __bfloat162float(qrow[mm*256 + h]);
    kl[i] = __bfloat162float(qrow[mm*256 + 128 + h]);
  }
  __syncthreads();
  if (t < 25){
    int mi = t/5, ki = t - 5*(t/5);
    float s = 0.f;
    for (int h=0; h<HID; h++) s += ql[mi*HID+h]*kl[ki*HID+h];
    lg[t] = s;
  }
  __syncthreads();
  if (t < 5){
    float mx = lg[t*5];
    for (int j=1;j<5;j++) mx = fmaxf(mx, lg[t*5+j]);
    float e[5], su=0.f;
    for (int j=0;j<5;j++){ e[j] = expf(lg[t*5+j]-mx); su += e[j]; }
    for (int j=0;j<5;j++) at[t*5+j] = e[j]/su;
  }
  __syncthreads();
  float bt = beta[0];
  for (int i=t; i<NCH*HID; i+=64){
    int mm = i>>7, h = i&127;
    float s = 0.f;
    #pragma unroll
    for (int k2=0;k2<5;k2++) s += at[mm*5+k2]*pl[k2*HID+h];
    outf[(long)node*(NCH*HID) + i] = __float2bfloat16(pl[i] + bt*s);
  }
}

// ---------------- final GEMM: out(ND,NZ) = A(ND,640) @ B(NZ,640)^T, f32 out ----------------
__global__ __launch_bounds__(256) void k_gemm_final(
    const bf16* __restrict__ Aout, const bf16* __restrict__ Bb, float* __restrict__ out)
{
  __shared__ short As[128*40];
  __shared__ short Bs[128*40];
  int t = threadIdx.x;
  int lane = t&63, wv=t>>6, wr=wv>>1, wc=wv&1;
  int row0 = blockIdx.x*128, col0 = blockIdx.y*128;
  const short* Ag = (const short*)Aout;
  const short* Bg = (const short*)Bb;
  int l15 = lane&15, kof = (lane>>4)*8;
  f4v acc[4][4] = {};
  for (int kk=0; kk<NCH*HID; kk+=32){
    int mch = kk>>7, h0 = kk&127;
    __syncthreads();
    #pragma unroll
    for (int j=0;j<2;j++){
      int c = t + j*256;
      int row = c>>2, sub = c&3;
      *(s8v*)(&As[row*40 + sub*8]) = *(const s8v*)(Ag + ((long)mch*ND + row0+row)*HID + h0 + sub*8);
      *(s8v*)(&Bs[row*40 + sub*8]) = *(const s8v*)(Bg + (long)(col0+row)*(NCH*HID) + kk + sub*8);
    }
    __syncthreads();
    s8v af[4], bg[4];
    #pragma unroll
    for (int i=0;i<4;i++){
      af[i] = *(const s8v*)(&As[(wr*64 + i*16 + l15)*40 + kof]);
      bg[i] = *(const s8v*)(&Bs[(wc*64 + i*16 + l15)*40 + kof]);
    }
    #pragma unroll
    for (int mi=0;mi<4;mi++)
      #pragma unroll
      for (int ni=0;ni<4;ni++)
        acc[mi][ni] = __builtin_amdgcn_mfma_f32_16x16x32_bf16(af[mi], bg[ni], acc[mi][ni],0,0,0);
  }
  #pragma unroll
  for (int mi=0;mi<4;mi++){
    #pragma unroll
    for (int ni=0;ni<4;ni++){
      int col = col0 + wc*64 + ni*16 + l15;
      #pragma unroll
      for (int r=0;r<4;r++){
        int row = row0 + wr*64 + mi*16 + (lane>>4)*4 + r;
        out[(long)row*NZ + col] = acc[mi][ni][r];
      }
    }
  }
}

extern "C" void kernel_launch(void* const* d_in, const int* in_sizes, int n_in,
                              void* d_out, int out_size, void* d_ws, size_t ws_size,
                              hipStream_t stream)
{
  (void)in_sizes; (void)n_in; (void)out_size;
  const float* feat_d = (const float*)d_in[0];
  const float* feat_z = (const float*)d_in[1];
  const float* att_d  = (const float*)d_in[2];
  const float* att_z  = (const float*)d_in[3];
  const int* src_d = (const int*)d_in[4];
  const int* dst_d = (const int*)d_in[5];
  const int* src_z = (const int*)d_in[6];
  const int* dst_z = (const int*)d_in[7];
  const float* dW1=(const float*)d_in[8];  const float* db1=(const float*)d_in[9];
  const float* dW2=(const float*)d_in[10]; const float* db2=(const float*)d_in[11];
  const float* dW3=(const float*)d_in[12]; const float* db3=(const float*)d_in[13];
  const float* Wq_d=(const float*)d_in[14]; const float* bq_d=(const float*)d_in[15];
  const float* Wk_d=(const float*)d_in[16]; const float* bk_d=(const float*)d_in[17];
  const float* beta_d=(const float*)d_in[18];
  const float* zW1=(const float*)d_in[19]; const float* zb1=(const float*)d_in[20];
  const float* zW2=(const float*)d_in[21]; const float* zb2=(const float*)d_in[22];
  const float* zW3=(const float*)d_in[23]; const float* zb3=(const float*)d_in[24];
  const float* Wq_z=(const float*)d_in[25]; const float* bq_z=(const float*)d_in[26];
  const float* Wk_z=(const float*)d_in[27]; const float* bk_z=(const float*)d_in[28];
  const float* beta_z=(const float*)d_in[29];
  const float* wattn=(const float*)d_in[30];
  const float* Wdec=(const float*)d_in[31]; const float* bdec=(const float*)d_in[32];

  char* ws = (char*)d_ws;
  size_t o = 0;
  auto alloc = [&](size_t bytes)->char*{
    size_t r = (o + 255) & ~(size_t)255;
    o = r + bytes;
    return ws + r;
  };
  bf16* featb_d = (bf16*)alloc((size_t)ND*IN_DIM*2);
  bf16* featb_z = (bf16*)alloc((size_t)NZ*IN_DIM*2);
  bf16* Y_d = (bf16*)alloc((size_t)NP*ND*MIDW*2);        // reused later as qk_z
  bf16* Y_z = (bf16*)alloc((size_t)NP*NZ*MIDW*2);        // reused later as Bbig
  bf16* h1_d = (bf16*)alloc((size_t)NCH*ND*MIDW*2);      // reused later as out_d
  bf16* h2_d = (bf16*)alloc((size_t)NCH*ND*MIDW*2);
  bf16* pbuf_d = (bf16*)alloc((size_t)ND*NCH*HID*2);
  bf16* qk_d = (bf16*)alloc((size_t)ND*NCH*256*2);
  bf16* h1_z = (bf16*)alloc((size_t)NCH*NZ*MIDW*2);      // reused later as out_z
  bf16* h2_z = (bf16*)alloc((size_t)NCH*NZ*MIDW*2);
  bf16* pbuf_z = (bf16*)alloc((size_t)NZ*NCH*HID*2);
  int* csr_d = (int*)alloc((size_t)NP*E_D*4);
  int* csr_z = (int*)alloc((size_t)NP*E_Z*4);
  int* degcur = (int*)alloc((size_t)(NP*ND*2 + NP*NZ*2)*4);
  int* deg_d = degcur;
  int* cur_d = deg_d + NP*ND;
  int* deg_z = cur_d + NP*ND;
  int* cur_z = deg_z + NP*NZ;
  int* off_d = (int*)alloc((size_t)NP*(ND+1)*4);
  int* off_z = (int*)alloc((size_t)NP*(NZ+1)*4);
  bf16* w1t_d = (bf16*)alloc((size_t)NCH*MIDW*IN_DIM*2);
  bf16* w2t_d = (bf16*)alloc((size_t)NCH*MIDW*MIDW*2);
  bf16* w3t_d = (bf16*)alloc((size_t)NCH*HID*MIDW*2);
  bf16* w1t_z = (bf16*)alloc((size_t)NCH*MIDW*IN_DIM*2);
  bf16* w2t_z = (bf16*)alloc((size_t)NCH*MIDW*MIDW*2);
  bf16* w3t_z = (bf16*)alloc((size_t)NCH*HID*MIDW*2);
  bf16* qkw_d = (bf16*)alloc((size_t)2*HID*HID*2);
  bf16* qkw_z = (bf16*)alloc((size_t)2*HID*HID*2);
  bf16* wdect = (bf16*)alloc((size_t)NCH*HID*HID*2);
  float* qkb_d = (float*)alloc((size_t)2*HID*4);
  float* qkb_z = (float*)alloc((size_t)2*HID*4);
  float* wsm   = (float*)alloc((size_t)NCH*4);
  bf16* out_d = h1_d;      // h1 dead after layer-2 GEMM
  bf16* out_z = h1_z;
  bf16* qk_z  = Y_d;       // Y_d dead after drug k_agg2 (qk_z needs 10.5MB <= 12.6MB)
  bf16* Bbig  = Y_z;       // Y_z dead after disease k_agg2 (5.2MB <= 6.3MB)
  if (ws_size < o) return;

  // CSR build
  hipMemsetAsync(degcur, 0, (size_t)(NP*ND*2 + NP*NZ*2)*4, stream);
  k_count_deg<<<NP*E_D/256, 256, 0, stream>>>(src_d, deg_d, E_D, ND);
  k_count_deg<<<NP*E_Z/256, 256, 0, stream>>>(src_z, deg_z, E_Z, NZ);
  k_scan<<<NP, 256, 0, stream>>>(deg_d, off_d, ND);
  k_scan<<<NP, 256, 0, stream>>>(deg_z, off_z, NZ);
  k_scatter<<<NP*E_D/256, 256, 0, stream>>>(src_d, dst_d, off_d, cur_d, csr_d, E_D, ND);
  k_scatter<<<NP*E_Z/256, 256, 0, stream>>>(src_z, dst_z, off_z, cur_z, csr_z, E_Z, NZ);
  // weight prep
  k_cvt_bf16<<<ND*IN_DIM/256, 256, 0, stream>>>(feat_d, featb_d, (long)ND*IN_DIM);
  k_cvt_bf16<<<NZ*IN_DIM/256, 256, 0, stream>>>(feat_z, featb_z, (long)NZ*IN_DIM);
  k_transpose<<<dim3(32,1,NCH),256,0,stream>>>(dW1, w1t_d, IN_DIM, MIDW);
  k_transpose<<<dim3(32,1,NCH),256,0,stream>>>(dW2, w2t_d, MIDW, MIDW);
  k_transpose<<<dim3(32,1,NCH),256,0,stream>>>(dW3, w3t_d, MIDW, HID);
  k_transpose<<<dim3(32,1,NCH),256,0,stream>>>(zW1, w1t_z, IN_DIM, MIDW);
  k_transpose<<<dim3(32,1,NCH),256,0,stream>>>(zW2, w2t_z, MIDW, MIDW);
  k_transpose<<<dim3(32,1,NCH),256,0,stream>>>(zW3, w3t_z, MIDW, HID);
  k_transpose<<<dim3(16,1,1),256,0,stream>>>(Wq_d, qkw_d, HID, HID);
  k_transpose<<<dim3(16,1,1),256,0,stream>>>(Wk_d, qkw_d + HID*HID, HID, HID);
  k_transpose<<<dim3(16,1,1),256,0,stream>>>(Wq_z, qkw_z, HID, HID);
  k_transpose<<<dim3(16,1,1),256,0,stream>>>(Wk_z, qkw_z + HID*HID, HID, HID);
  k_transpose<<<dim3(32,1,NCH),256,0,stream>>>(Wdec, wdect, HID, HID);
  hipMemcpyAsync(qkb_d, bq_d, HID*4, hipMemcpyDeviceToDevice, stream);
  hipMemcpyAsync(qkb_d+HID, bk_d, HID*4, hipMemcpyDeviceToDevice, stream);
  hipMemcpyAsync(qkb_z, bq_z, HID*4, hipMemcpyDeviceToDevice, stream);
  hipMemcpyAsync(qkb_z+HID, bk_z, HID*4, hipMemcpyDeviceToDevice, stream);
  k_softmax5<<<1,64,0,stream>>>(wattn, wsm);

  // ===== drug pipeline =====
  // channel 0: h1_0 = relu(feat @ W1_0 + b1_0)
  k_gemm<true,false,false><<<dim3(ND/128, MIDW/64, 1),256,0,stream>>>(featb_d, w1t_d, db1, h1_d,
      nullptr, nullptr, 0L, IN_DIM, MIDW, 0L, (long)MIDW, 0L);
  // Y_m = att_m * (feat @ W1_{m+1}), m = 0..3
  k_gemm<false,false,true><<<dim3(ND/128, MIDW/64, NP),256,0,stream>>>(featb_d, w1t_d + MIDW*IN_DIM,
      nullptr, Y_d, nullptr, att_d, (long)ND, IN_DIM, MIDW, 0L, (long)MIDW, (long)ND*MIDW);
  // aggregate Y -> h1 channels 1..4 (fused bias+relu)
  k_agg2<<<NP*ND/4, 256, 0, stream>>>(csr_d, off_d, db1, Y_d, h1_d, ND, E_D);
  // layer 2 + 3
  k_gemm<true,false,false><<<dim3(ND/128, MIDW/64, NCH),256,0,stream>>>(h1_d, w2t_d, db2, h2_d,
      nullptr, nullptr, 0L, MIDW, MIDW, (long)ND*MIDW, (long)MIDW, (long)ND*MIDW);
  k_gemm<false,false,false><<<dim3(ND/128, HID/64, NCH),256,0,stream>>>(h2_d, w3t_d, db3, pbuf_d,
      nullptr, nullptr, 0L, MIDW, HID, (long)ND*MIDW, (long)NCH*HID, (long)HID);
  // fused Q|K: (ND*NCH,128) @ (256,128)^T
  k_gemm<false,false,false><<<dim3(ND*NCH/128, 256/64, 1),256,0,stream>>>(pbuf_d, qkw_d, qkb_d, qk_d,
      nullptr, nullptr, 0L, HID, 256, 0L, 256L, 0L);

  // ===== disease pipeline =====
  k_gemm<true,false,false><<<dim3(NZ/128, MIDW/64, 1),256,0,stream>>>(featb_z, w1t_z, zb1, h1_z,
      nullptr, nullptr, 0L, IN_DIM, MIDW, 0L, (long)MIDW, 0L);
  k_gemm<false,false,true><<<dim3(NZ/128, MIDW/64, NP),256,0,stream>>>(featb_z, w1t_z + MIDW*IN_DIM,
      nullptr, Y_z, nullptr, att_z, (long)NZ, IN_DIM, MIDW, 0L, (long)MIDW, (long)NZ*MIDW);
  k_agg2<<<NP*NZ/4, 256, 0, stream>>>(csr_z, off_z, zb1, Y_z, h1_z, NZ, E_Z);
  k_gemm<true,false,false><<<dim3(NZ/128, MIDW/64, NCH),256,0,stream>>>(h1_z, w2t_z, zb2, h2_z,
      nullptr, nullptr, 0L, MIDW, MIDW, (long)NZ*MIDW, (long)MIDW, (long)NZ*MIDW);
  k_gemm<false,false,false><<<dim3(NZ/128, HID/64, NCH),256,0,stream>>>(h2_z, w3t_z, zb3, pbuf_z,
      nullptr, nullptr, 0L, MIDW, HID, (long)NZ*MIDW, (long)NCH*HID, (long)HID);
  k_gemm<false,false,false><<<dim3(NZ*NCH/128, 256/64, 1),256,0,stream>>>(pbuf_z, qkw_z, qkb_z, qk_z,
      nullptr, nullptr, 0L, HID, 256, 0L, 256L, 0L);

  // metapath attention (node-major out == faithful .view buffer)
  k_attn<<<ND, 64, 0, stream>>>(pbuf_d, qk_d, beta_d, out_d, ND);
  k_attn<<<NZ, 64, 0, stream>>>(pbuf_z, qk_z, beta_z, out_z, NZ);
  // decoder: Bbig[z, m*128+h] = w_m * (out_z_view[m] @ Wdec[m] + bdec[m])
  k_gemm<false,true,false><<<dim3(NZ/128, HID/64, NCH),256,0,stream>>>(out_z, wdect, bdec, Bbig,
      wsm, nullptr, 0L, HID, HID, (long)NZ*HID, (long)NCH*HID, (long)HID);
  // final: out = A(ND,640) @ Bbig(NZ,640)^T
  k_gemm_final<<<dim3(ND/128, NZ/128), 256, 0, stream>>>(out_d, Bbig, (float*)d_out);
}

// Round 3
// 420.061 us; speedup vs baseline: 1.4692x; 1.3515x over previous
//
#include <hip/hip_runtime.h>
#include <hip/hip_bf16.h>

#define ND 8192
#define NZ 4096
#define IN_DIM 256
#define HID 128
#define MIDW 192
#define NP 4
#define NCH 5
#define DEG 32
#define E_D (ND*DEG)
#define E_Z (NZ*DEG)

typedef __hip_bfloat16 bf16;
typedef __attribute__((ext_vector_type(8))) short s8v;
typedef __attribute__((ext_vector_type(4))) float f4v;

static __device__ __forceinline__ unsigned short f2bf(float x){
  bf16 b = __float2bfloat16(x);
  return *reinterpret_cast<unsigned short*>(&b);
}
static __device__ __forceinline__ uint packbf2(float a, float b){
  return (uint)f2bf(a) | ((uint)f2bf(b) << 16);
}

// ---------------- CSR build (drug+disease merged) ----------------
__global__ void k_count(const int* __restrict__ src_d, int* __restrict__ deg_d,
                        const int* __restrict__ src_z, int* __restrict__ deg_z){
  long i = (long)blockIdx.x*blockDim.x + threadIdx.x;
  if (i < (long)NP*E_D){
    int m = (int)(i / E_D);
    atomicAdd(&deg_d[m*ND + src_d[i]], 1);
  } else {
    long j = i - (long)NP*E_D;
    int m = (int)(j / E_Z);
    atomicAdd(&deg_z[m*NZ + src_z[j]], 1);
  }
}

__global__ __launch_bounds__(256) void k_scan(const int* __restrict__ deg_d, int* __restrict__ off_d,
                                              const int* __restrict__ deg_z, int* __restrict__ off_z){
  int b = blockIdx.x;
  const int* d; int* o; int n;
  if (b < NP){ d = deg_d + (long)b*ND; o = off_d + (long)b*(ND+1); n = ND; }
  else { int m = b-NP; d = deg_z + (long)m*NZ; o = off_z + (long)m*(NZ+1); n = NZ; }
  int t = threadIdx.x, lane = t&63, wv = t>>6;
  __shared__ int wsum[4];
  __shared__ int carry;
  if (t==0) carry = 0;
  __syncthreads();
  for (int base=0; base<n; base+=256){
    int v = d[base+t];
    int x = v;
    #pragma unroll
    for (int s=1; s<64; s<<=1){
      int u = __shfl_up(x, s, 64);
      if (lane >= s) x += u;
    }
    if (lane==63) wsum[wv] = x;
    __syncthreads();
    int wo = 0;
    for (int w=0; w<wv; w++) wo += wsum[w];
    int c = carry;
    o[base+t] = c + wo + x - v;
    __syncthreads();
    if (t==255) carry = c + wo + x;
  }
  __syncthreads();
  if (t==0) o[n] = carry;
}

__global__ void k_scatter(const int* __restrict__ src_d, const int* __restrict__ dst_d,
                          const int* __restrict__ off_d, int* __restrict__ cur_d, int* __restrict__ csr_d,
                          const int* __restrict__ src_z, const int* __restrict__ dst_z,
                          const int* __restrict__ off_z, int* __restrict__ cur_z, int* __restrict__ csr_z){
  long i = (long)blockIdx.x*blockDim.x + threadIdx.x;
  if (i < (long)NP*E_D){
    int m = (int)(i / E_D);
    int s = src_d[i];
    int pos = atomicAdd(&cur_d[m*ND + s], 1);
    csr_d[(long)m*E_D + off_d[(long)m*(ND+1) + s] + pos] = dst_d[i];
  } else {
    long j = i - (long)NP*E_D;
    int m = (int)(j / E_Z);
    int s = src_z[j];
    int pos = atomicAdd(&cur_z[m*NZ + s], 1);
    csr_z[(long)m*E_Z + off_z[(long)m*(NZ+1) + s] + pos] = dst_z[j];
  }
}

// ---------------- mega prep: cvts + all transposes + bias packs + softmax ----------------
static __device__ __forceinline__ void tpz(const float* __restrict__ in, bf16* __restrict__ out,
                                           int rows, int cols, long idx){
  int per = rows*cols;
  int b = (int)(idx / per);
  int rem = (int)(idx - (long)b*per);
  int r = rem / cols, c = rem - r*cols;
  out[(long)b*per + (long)c*rows + r] = __float2bfloat16(in[idx]);
}

#define PB0 2048          // cvt_d  (ND*256/4/256)
#define PB1 (PB0+1024)    // cvt_z
#define PB2 (PB1+960)     // w1t_d  5*256*192
#define PB3 (PB2+960)     // w1t_z
#define PB4 (PB3+720)     // w2t_d  5*192*192
#define PB5 (PB4+720)     // w2t_z
#define PB6 (PB5+480)     // w3t_d  5*192*128
#define PB7 (PB6+480)     // w3t_z
#define PB8 (PB7+128)     // qkw_d  2*128*128
#define PB9 (PB8+128)     // qkw_z
#define PB10 (PB9+320)    // wdect  5*128*128
#define PB11 (PB10+1)     // misc

__global__ __launch_bounds__(256) void k_prep(
    const float* feat_d, const float* feat_z, bf16* featb_d, bf16* featb_z,
    const float* dW1, const float* dW2, const float* dW3,
    const float* zW1, const float* zW2, const float* zW3,
    const float* Wq_d, const float* Wk_d, const float* Wq_z, const float* Wk_z,
    const float* Wdec,
    bf16* w1t_d, bf16* w2t_d, bf16* w3t_d, bf16* w1t_z, bf16* w2t_z, bf16* w3t_z,
    bf16* qkw_d, bf16* qkw_z, bf16* wdect,
    const float* bq_d, const float* bk_d, const float* bq_z, const float* bk_z,
    float* qkb_d, float* qkb_z, const float* wattn, float* wsm)
{
  int b = blockIdx.x, t = threadIdx.x;
  if (b < PB0){
    long i4 = (long)b*256 + t;
    float4 v = ((const float4*)feat_d)[i4];
    ushort4 o; o.x=f2bf(v.x); o.y=f2bf(v.y); o.z=f2bf(v.z); o.w=f2bf(v.w);
    ((ushort4*)featb_d)[i4] = o;
  } else if (b < PB1){
    long i4 = (long)(b-PB0)*256 + t;
    float4 v = ((const float4*)feat_z)[i4];
    ushort4 o; o.x=f2bf(v.x); o.y=f2bf(v.y); o.z=f2bf(v.z); o.w=f2bf(v.w);
    ((ushort4*)featb_z)[i4] = o;
  } else if (b < PB2){ tpz(dW1, w1t_d, IN_DIM, MIDW, (long)(b-PB1)*256 + t); }
  else if (b < PB3){ tpz(zW1, w1t_z, IN_DIM, MIDW, (long)(b-PB2)*256 + t); }
  else if (b < PB4){ tpz(dW2, w2t_d, MIDW, MIDW, (long)(b-PB3)*256 + t); }
  else if (b < PB5){ tpz(zW2, w2t_z, MIDW, MIDW, (long)(b-PB4)*256 + t); }
  else if (b < PB6){ tpz(dW3, w3t_d, MIDW, HID, (long)(b-PB5)*256 + t); }
  else if (b < PB7){ tpz(zW3, w3t_z, MIDW, HID, (long)(b-PB6)*256 + t); }
  else if (b < PB8){
    long idx = (long)(b-PB7)*256 + t;
    if (idx < 16384) tpz(Wq_d, qkw_d, HID, HID, idx);
    else tpz(Wk_d, qkw_d + 16384, HID, HID, idx - 16384);
  } else if (b < PB9){
    long idx = (long)(b-PB8)*256 + t;
    if (idx < 16384) tpz(Wq_z, qkw_z, HID, HID, idx);
    else tpz(Wk_z, qkw_z + 16384, HID, HID, idx - 16384);
  } else if (b < PB10){ tpz(Wdec, wdect, HID, HID, (long)(b-PB9)*256 + t); }
  else {
    if (t < 128){ qkb_d[t] = bq_d[t]; qkb_z[t] = bq_z[t]; }
    else { qkb_d[t] = bk_d[t-128]; qkb_z[t] = bk_z[t-128]; }
    if (t == 0){
      float mx = wattn[0];
      for (int i=1;i<NCH;i++) mx = fmaxf(mx, wattn[i]);
      float e[NCH], s=0.f;
      for (int i=0;i<NCH;i++){ e[i]=expf(wattn[i]-mx); s+=e[i]; }
      for (int i=0;i<NCH;i++) wsm[i]=e[i]/s;
    }
  }
}

// ---------------- aggregation (drug+disease merged, 4-edge unroll) ----------------
__global__ __launch_bounds__(256) void k_agg2(
    const int* __restrict__ csr_d, const int* __restrict__ off_d, const float* __restrict__ bias_d,
    const bf16* __restrict__ Y_d, bf16* __restrict__ h1_d,
    const int* __restrict__ csr_z, const int* __restrict__ off_z, const float* __restrict__ bias_z,
    const bf16* __restrict__ Y_z, bf16* __restrict__ h1_z)
{
  int wid = (blockIdx.x*256 + threadIdx.x) >> 6;
  int lane = threadIdx.x & 63;
  const int *csr, *off; const float* bias; const uint* Yb; bf16* h1; int n, E, m;
  if (wid < NP*ND){
    m = wid >> 13; int s0 = wid & (ND-1);
    csr = csr_d; off = off_d; bias = bias_d; h1 = h1_d; n = ND; E = E_D;
    Yb = (const uint*)Y_d + (long)m*ND*96;
    wid = s0;
  } else {
    int w2 = wid - NP*ND;
    m = w2 >> 12; int s0 = w2 & (NZ-1);
    csr = csr_z; off = off_z; bias = bias_z; h1 = h1_z; n = NZ; E = E_Z;
    Yb = (const uint*)Y_z + (long)m*NZ*96;
    wid = s0;
  }
  int s = wid;
  int o0 = off[(long)m*(n+1)+s], o1 = off[(long)m*(n+1)+s+1];
  const int* lst = csr + (long)m*E;
  bool hi = lane < 32;
  float a0=0.f,a1=0.f,a2=0.f,a3=0.f;
  int i = o0;
  for (; i+3 < o1; i += 4){
    const uint* r0 = Yb + (long)lst[i]*96;
    const uint* r1 = Yb + (long)lst[i+1]*96;
    const uint* r2 = Yb + (long)lst[i+2]*96;
    const uint* r3 = Yb + (long)lst[i+3]*96;
    uint w0 = r0[lane], w1 = r1[lane], w2 = r2[lane], w3 = r3[lane];
    uint v0 = hi ? r0[64+lane] : 0u;
    uint v1 = hi ? r1[64+lane] : 0u;
    uint v2 = hi ? r2[64+lane] : 0u;
    uint v3 = hi ? r3[64+lane] : 0u;
    a0 += __uint_as_float(w0<<16) + __uint_as_float(w1<<16) + __uint_as_float(w2<<16) + __uint_as_float(w3<<16);
    a1 += __uint_as_float(w0&0xffff0000u) + __uint_as_float(w1&0xffff0000u) + __uint_as_float(w2&0xffff0000u) + __uint_as_float(w3&0xffff0000u);
    a2 += __uint_as_float(v0<<16) + __uint_as_float(v1<<16) + __uint_as_float(v2<<16) + __uint_as_float(v3<<16);
    a3 += __uint_as_float(v0&0xffff0000u) + __uint_as_float(v1&0xffff0000u) + __uint_as_float(v2&0xffff0000u) + __uint_as_float(v3&0xffff0000u);
  }
  for (; i < o1; i++){
    const uint* r0 = Yb + (long)lst[i]*96;
    uint w0 = r0[lane];
    uint v0 = hi ? r0[64+lane] : 0u;
    a0 += __uint_as_float(w0<<16);
    a1 += __uint_as_float(w0&0xffff0000u);
    a2 += __uint_as_float(v0<<16);
    a3 += __uint_as_float(v0&0xffff0000u);
  }
  float inv = 1.0f / fmaxf((float)(o1-o0), 1.0f);
  const float* bb = bias + (m+1)*MIDW;
  float2 b0 = *(const float2*)(bb + 2*lane);
  uint* hrow = (uint*)((short*)h1 + ((long)(m+1)*n + s)*MIDW);
  hrow[lane] = packbf2(fmaxf(a0*inv + b0.x, 0.f), fmaxf(a1*inv + b0.y, 0.f));
  if (hi){
    float2 b1v = *(const float2*)(bb + 128 + 2*lane);
    hrow[64+lane] = packbf2(fmaxf(a2*inv + b1v.x, 0.f), fmaxf(a3*inv + b1v.y, 0.f));
  }
}

// ---------------- batched bf16 GEMM (two param sets, z-split), 128x64 tile ----------------
struct GemmP {
  const bf16* A; const bf16* BT; const float* bias; bf16* out;
  const float* scale; const float* rowsc;
  long rs_moff, a_moff, out_rstride, out_moff;
  int K, N, nrows;
};

template<bool RELU, bool HAS_SCALE, bool ROWSC>
__global__ __launch_bounds__(256) void k_gemm(GemmP P0, GemmP P1, int zsplit)
{
  const GemmP& p = ((int)blockIdx.z < zsplit) ? P0 : P1;
  int m = ((int)blockIdx.z < zsplit) ? blockIdx.z : blockIdx.z - zsplit;
  long row0 = (long)blockIdx.x*128;
  if (row0 >= p.nrows) return;
  int col0 = blockIdx.y*64;
  if (col0 >= p.N) return;
  __shared__ short As[128*40];
  __shared__ short Bs[64*40];
  int t = threadIdx.x;
  const short* Ag = (const short*)p.A + m*p.a_moff;
  const short* Bg = (const short*)p.BT + (long)m*p.N*p.K;
  int lane = t&63, wv = t>>6;
  int l15 = lane&15, kof = (lane>>4)*8;
  int K = p.K;
  f4v acc[2][4] = {};
  for (int kk=0; kk<K; kk+=32){
    __syncthreads();
    #pragma unroll
    for (int j=0;j<2;j++){
      int c = t + j*256;
      int row = c>>2, sub = c&3;
      *(s8v*)(&As[row*40 + sub*8]) = *(const s8v*)(Ag + (row0+row)*K + kk + sub*8);
    }
    { int row = t>>2, sub = t&3;
      *(s8v*)(&Bs[row*40 + sub*8]) = *(const s8v*)(Bg + (long)(col0+row)*K + kk + sub*8); }
    __syncthreads();
    s8v af[2], bfr[4];
    #pragma unroll
    for (int i2=0;i2<2;i2++) af[i2] = *(const s8v*)(&As[(wv*32 + i2*16 + l15)*40 + kof]);
    #pragma unroll
    for (int j2=0;j2<4;j2++) bfr[j2] = *(const s8v*)(&Bs[(j2*16 + l15)*40 + kof]);
    #pragma unroll
    for (int i2=0;i2<2;i2++)
      #pragma unroll
      for (int j2=0;j2<4;j2++)
        acc[i2][j2] = __builtin_amdgcn_mfma_f32_16x16x32_bf16(af[i2], bfr[j2], acc[i2][j2],0,0,0);
  }
  float sc = HAS_SCALE ? p.scale[m] : 1.0f;
  #pragma unroll
  for (int i2=0;i2<2;i2++){
    #pragma unroll
    for (int j2=0;j2<4;j2++){
      int col = col0 + j2*16 + l15;
      float bv = p.bias ? p.bias[m*p.N + col] : 0.f;
      #pragma unroll
      for (int r=0;r<4;r++){
        long row = row0 + wv*32 + i2*16 + (lane>>4)*4 + r;
        float v = acc[i2][j2][r] + bv;
        if (RELU) v = fmaxf(v, 0.f);
        v *= sc;
        if (ROWSC) v *= p.rowsc[m*p.rs_moff + row];
        p.out[m*p.out_moff + row*p.out_rstride + col] = __float2bfloat16(v);
      }
    }
  }
}

// ---------------- per-node metapath attention (merged d+z, one wave per node) ----------------
__global__ __launch_bounds__(64) void k_attn(
    const bf16* __restrict__ p_d, const bf16* __restrict__ qk_d, const float* __restrict__ beta_d,
    bf16* __restrict__ o_d,
    const bf16* __restrict__ p_z, const bf16* __restrict__ qk_z, const float* __restrict__ beta_z,
    bf16* __restrict__ o_z)
{
  int node = blockIdx.x; int t = threadIdx.x;
  const bf16 *pp, *qrow; bf16* outp; const float* betap;
  if (node < ND){
    pp = p_d + (long)node*(NCH*HID); qrow = qk_d + (long)node*NCH*256;
    outp = o_d + (long)node*(NCH*HID); betap = beta_d;
  } else {
    int nz = node - ND;
    pp = p_z + (long)nz*(NCH*HID); qrow = qk_z + (long)nz*NCH*256;
    outp = o_z + (long)nz*(NCH*HID); betap = beta_z;
  }
  __shared__ float pl[NCH*HID], ql[NCH*HID], kl[NCH*HID];
  __shared__ float lg[25], at[25];
  for (int i=t; i<NCH*HID; i+=64){
    int mm = i>>7, h = i&127;
    pl[i] = __bfloat162float(pp[i]);
    ql[i] = __bfloat162float(qrow[mm*256 + h]);
    kl[i] = __bfloat162float(qrow[mm*256 + 128 + h]);
  }
  __syncthreads();
  if (t < 50){
    int pr = t>>1, sub = t&1;
    int mi = pr/5, ki = pr - 5*mi;
    float s = 0.f;
    int h0 = sub*64;
    for (int h=h0; h<h0+64; h++) s += ql[mi*HID+h]*kl[ki*HID+h];
    s += __shfl_xor(s, 1);
    if (sub==0) lg[pr] = s;
  }
  __syncthreads();
  if (t < 5){
    float mx = lg[t*5];
    for (int j=1;j<5;j++) mx = fmaxf(mx, lg[t*5+j]);
    float e[5], su=0.f;
    for (int j=0;j<5;j++){ e[j] = expf(lg[t*5+j]-mx); su += e[j]; }
    for (int j=0;j<5;j++) at[t*5+j] = e[j]/su;
  }
  __syncthreads();
  float bt = betap[0];
  for (int i=t; i<NCH*HID; i+=64){
    int mm = i>>7, h = i&127;
    float s = 0.f;
    #pragma unroll
    for (int k2=0;k2<5;k2++) s += at[mm*5+k2]*pl[k2*HID+h];
    outp[i] = __float2bfloat16(pl[i] + bt*s);
  }
}

// ---------------- final GEMM: out(ND,NZ)=A(ND,640)@B(NZ,640)^T, swizzled LDS, BK=64 ----------------
__global__ __launch_bounds__(256) void k_gemm_final(
    const bf16* __restrict__ Aout, const bf16* __restrict__ Bb, float* __restrict__ out)
{
  __shared__ short As[128*64];
  __shared__ short Bs[128*64];
  int t = threadIdx.x;
  int lane = t&63, wv=t>>6, wr=wv>>1, wc=wv&1;
  int id = blockIdx.x;
  int wg = (id&7)*256 + (id>>3);          // bijective XCD swizzle (2048 % 8 == 0)
  int row0 = (wg&63)*128, col0 = (wg>>6)*128;
  const short* Ag = (const short*)Aout;
  const short* Bg = (const short*)Bb;
  int l15 = lane&15, hi = lane>>4;
  f4v acc[4][4] = {};
  for (int kk=0; kk<NCH*HID; kk+=64){
    int mch = kk>>7, h0 = kk&127;
    s8v av[4], bv[4];
    #pragma unroll
    for (int j=0;j<4;j++){
      int c = j*256 + t;
      int row = c>>3, seg = c&7;
      av[j] = *(const s8v*)(Ag + ((long)mch*ND + row0+row)*HID + h0 + seg*8);
      bv[j] = *(const s8v*)(Bg + (long)(col0+row)*(NCH*HID) + kk + seg*8);
    }
    __syncthreads();
    #pragma unroll
    for (int j=0;j<4;j++){
      int c = j*256 + t;
      int row = c>>3, seg = c&7;
      int sw = ((seg ^ (row&7))*8);
      *(s8v*)(&As[row*64 + sw]) = av[j];
      *(s8v*)(&Bs[row*64 + sw]) = bv[j];
    }
    __syncthreads();
    #pragma unroll
    for (int sl=0; sl<2; sl++){
      s8v af[4], bg[4];
      #pragma unroll
      for (int i=0;i<4;i++){
        int ra = wr*64 + i*16 + l15;
        af[i] = *(const s8v*)(&As[ra*64 + (((sl*4+hi) ^ (ra&7))*8)]);
        int rb = wc*64 + i*16 + l15;
        bg[i] = *(const s8v*)(&Bs[rb*64 + (((sl*4+hi) ^ (rb&7))*8)]);
      }
      #pragma unroll
      for (int mi=0;mi<4;mi++)
        #pragma unroll
        for (int ni=0;ni<4;ni++)
          acc[mi][ni] = __builtin_amdgcn_mfma_f32_16x16x32_bf16(af[mi], bg[ni], acc[mi][ni],0,0,0);
    }
  }
  #pragma unroll
  for (int mi=0;mi<4;mi++){
    #pragma unroll
    for (int ni=0;ni<4;ni++){
      int col = col0 + wc*64 + ni*16 + l15;
      #pragma unroll
      for (int r=0;r<4;r++){
        int row = row0 + wr*64 + mi*16 + hi*4 + r;
        out[(long)row*NZ + col] = acc[mi][ni][r];
      }
    }
  }
}

extern "C" void kernel_launch(void* const* d_in, const int* in_sizes, int n_in,
                              void* d_out, int out_size, void* d_ws, size_t ws_size,
                              hipStream_t stream)
{
  (void)in_sizes; (void)n_in; (void)out_size;
  const float* feat_d = (const float*)d_in[0];
  const float* feat_z = (const float*)d_in[1];
  const float* att_d  = (const float*)d_in[2];
  const float* att_z  = (const float*)d_in[3];
  const int* src_d = (const int*)d_in[4];
  const int* dst_d = (const int*)d_in[5];
  const int* src_z = (const int*)d_in[6];
  const int* dst_z = (const int*)d_in[7];
  const float* dW1=(const float*)d_in[8];  const float* db1=(const float*)d_in[9];
  const float* dW2=(const float*)d_in[10]; const float* db2=(const float*)d_in[11];
  const float* dW3=(const float*)d_in[12]; const float* db3=(const float*)d_in[13];
  const float* Wq_d=(const float*)d_in[14]; const float* bq_d=(const float*)d_in[15];
  const float* Wk_d=(const float*)d_in[16]; const float* bk_d=(const float*)d_in[17];
  const float* beta_d=(const float*)d_in[18];
  const float* zW1=(const float*)d_in[19]; const float* zb1=(const float*)d_in[20];
  const float* zW2=(const float*)d_in[21]; const float* zb2=(const float*)d_in[22];
  const float* zW3=(const float*)d_in[23]; const float* zb3=(const float*)d_in[24];
  const float* Wq_z=(const float*)d_in[25]; const float* bq_z=(const float*)d_in[26];
  const float* Wk_z=(const float*)d_in[27]; const float* bk_z=(const float*)d_in[28];
  const float* beta_z=(const float*)d_in[29];
  const float* wattn=(const float*)d_in[30];
  const float* Wdec=(const float*)d_in[31]; const float* bdec=(const float*)d_in[32];

  char* ws = (char*)d_ws;
  size_t o = 0;
  auto alloc = [&](size_t bytes)->char*{
    size_t r = (o + 255) & ~(size_t)255;
    o = r + bytes;
    return ws + r;
  };
  bf16* featb_d = (bf16*)alloc((size_t)ND*IN_DIM*2);
  bf16* featb_z = (bf16*)alloc((size_t)NZ*IN_DIM*2);
  bf16* Y_d = (bf16*)alloc((size_t)NP*ND*MIDW*2);        // reused later as qk_z
  bf16* Y_z = (bf16*)alloc((size_t)NP*NZ*MIDW*2);        // reused later as Bbig
  bf16* h1_d = (bf16*)alloc((size_t)NCH*ND*MIDW*2);      // reused later as out_d
  bf16* h2_d = (bf16*)alloc((size_t)NCH*ND*MIDW*2);
  bf16* pbuf_d = (bf16*)alloc((size_t)ND*NCH*HID*2);
  bf16* qk_d = (bf16*)alloc((size_t)ND*NCH*256*2);
  bf16* h1_z = (bf16*)alloc((size_t)NCH*NZ*MIDW*2);      // reused later as out_z
  bf16* h2_z = (bf16*)alloc((size_t)NCH*NZ*MIDW*2);
  bf16* pbuf_z = (bf16*)alloc((size_t)NZ*NCH*HID*2);
  int* csr_d = (int*)alloc((size_t)NP*E_D*4);
  int* csr_z = (int*)alloc((size_t)NP*E_Z*4);
  int* degcur = (int*)alloc((size_t)(NP*ND*2 + NP*NZ*2)*4);
  int* deg_d = degcur;
  int* cur_d = deg_d + NP*ND;
  int* deg_z = cur_d + NP*ND;
  int* cur_z = deg_z + NP*NZ;
  int* off_d = (int*)alloc((size_t)NP*(ND+1)*4);
  int* off_z = (int*)alloc((size_t)NP*(NZ+1)*4);
  bf16* w1t_d = (bf16*)alloc((size_t)NCH*MIDW*IN_DIM*2);
  bf16* w2t_d = (bf16*)alloc((size_t)NCH*MIDW*MIDW*2);
  bf16* w3t_d = (bf16*)alloc((size_t)NCH*HID*MIDW*2);
  bf16* w1t_z = (bf16*)alloc((size_t)NCH*MIDW*IN_DIM*2);
  bf16* w2t_z = (bf16*)alloc((size_t)NCH*MIDW*MIDW*2);
  bf16* w3t_z = (bf16*)alloc((size_t)NCH*HID*MIDW*2);
  bf16* qkw_d = (bf16*)alloc((size_t)2*HID*HID*2);
  bf16* qkw_z = (bf16*)alloc((size_t)2*HID*HID*2);
  bf16* wdect = (bf16*)alloc((size_t)NCH*HID*HID*2);
  float* qkb_d = (float*)alloc((size_t)2*HID*4);
  float* qkb_z = (float*)alloc((size_t)2*HID*4);
  float* wsm   = (float*)alloc((size_t)NCH*4);
  bf16* out_d = h1_d;
  bf16* out_z = h1_z;
  bf16* qk_z  = Y_d;
  bf16* Bbig  = Y_z;
  if (ws_size < o) return;

  hipMemsetAsync(degcur, 0, (size_t)(NP*ND*2 + NP*NZ*2)*4, stream);
  k_prep<<<PB11, 256, 0, stream>>>(feat_d, feat_z, featb_d, featb_z,
      dW1, dW2, dW3, zW1, zW2, zW3, Wq_d, Wk_d, Wq_z, Wk_z, Wdec,
      w1t_d, w2t_d, w3t_d, w1t_z, w2t_z, w3t_z, qkw_d, qkw_z, wdect,
      bq_d, bk_d, bq_z, bk_z, qkb_d, qkb_z, wattn, wsm);
  k_count<<<(NP*E_D + NP*E_Z)/256, 256, 0, stream>>>(src_d, deg_d, src_z, deg_z);
  k_scan<<<2*NP, 256, 0, stream>>>(deg_d, off_d, deg_z, off_z);
  k_scatter<<<(NP*E_D + NP*E_Z)/256, 256, 0, stream>>>(src_d, dst_d, off_d, cur_d, csr_d,
                                                       src_z, dst_z, off_z, cur_z, csr_z);

  // stage A1: channel-0 h1 = relu(feat @ W1_0 + b1_0), drug+disease
  {
    GemmP pd = {featb_d, w1t_d, db1, h1_d, nullptr, nullptr, 0, 0, MIDW, 0, IN_DIM, MIDW, ND};
    GemmP pz = {featb_z, w1t_z, zb1, h1_z, nullptr, nullptr, 0, 0, MIDW, 0, IN_DIM, MIDW, NZ};
    k_gemm<true,false,false><<<dim3(64, 3, 2), 256, 0, stream>>>(pd, pz, 1);
  }
  // stage A2: Y_m = att_m * (feat @ W1_{m+1}), drug(4) + disease(4)
  {
    GemmP pd = {featb_d, w1t_d + MIDW*IN_DIM, nullptr, Y_d, nullptr, att_d, ND, 0, MIDW, (long)ND*MIDW, IN_DIM, MIDW, ND};
    GemmP pz = {featb_z, w1t_z + MIDW*IN_DIM, nullptr, Y_z, nullptr, att_z, NZ, 0, MIDW, (long)NZ*MIDW, IN_DIM, MIDW, NZ};
    k_gemm<false,false,true><<<dim3(64, 3, 8), 256, 0, stream>>>(pd, pz, 4);
  }
  // aggregation -> h1 channels 1..4 (both types)
  k_agg2<<<(NP*ND + NP*NZ)/4, 256, 0, stream>>>(csr_d, off_d, db1, Y_d, h1_d,
                                                csr_z, off_z, zb1, Y_z, h1_z);
  // layer 2 (both, 10 channels)
  {
    GemmP pd = {h1_d, w2t_d, db2, h2_d, nullptr, nullptr, 0, (long)ND*MIDW, MIDW, (long)ND*MIDW, MIDW, MIDW, ND};
    GemmP pz = {h1_z, w2t_z, zb2, h2_z, nullptr, nullptr, 0, (long)NZ*MIDW, MIDW, (long)NZ*MIDW, MIDW, MIDW, NZ};
    k_gemm<true,false,false><<<dim3(64, 3, 10), 256, 0, stream>>>(pd, pz, 5);
  }
  // layer 3 (both) -> pbuf node-major (n, M, H)
  {
    GemmP pd = {h2_d, w3t_d, db3, pbuf_d, nullptr, nullptr, 0, (long)ND*MIDW, (long)NCH*HID, HID, MIDW, HID, ND};
    GemmP pz = {h2_z, w3t_z, zb3, pbuf_z, nullptr, nullptr, 0, (long)NZ*MIDW, (long)NCH*HID, HID, MIDW, HID, NZ};
    k_gemm<false,false,false><<<dim3(64, 2, 10), 256, 0, stream>>>(pd, pz, 5);
  }
  // fused Q|K (both)
  {
    GemmP pd = {pbuf_d, qkw_d, qkb_d, qk_d, nullptr, nullptr, 0, 0, 256, 0, HID, 256, ND*NCH};
    GemmP pz = {pbuf_z, qkw_z, qkb_z, qk_z, nullptr, nullptr, 0, 0, 256, 0, HID, 256, NZ*NCH};
    k_gemm<false,false,false><<<dim3(320, 4, 2), 256, 0, stream>>>(pd, pz, 1);
  }
  // metapath attention (both)
  k_attn<<<ND + NZ, 64, 0, stream>>>(pbuf_d, qk_d, beta_d, out_d,
                                     pbuf_z, qk_z, beta_z, out_z);
  // decoder: Bbig[z, m*128+h] = w_m * (out_z_view[m] @ Wdec[m] + bdec[m])
  {
    GemmP pz = {out_z, wdect, bdec, Bbig, wsm, nullptr, 0, (long)NZ*HID, (long)NCH*HID, HID, HID, HID, NZ};
    k_gemm<false,true,false><<<dim3(32, 2, 5), 256, 0, stream>>>(pz, pz, 5);
  }
  // final
  k_gemm_final<<<2048, 256, 0, stream>>>(out_d, Bbig, (float*)d_out);
}

// Round 4
// 412.435 us; speedup vs baseline: 1.4963x; 1.0185x over previous
//
#include <hip/hip_runtime.h>
#include <hip/hip_bf16.h>

#define ND 8192
#define NZ 4096
#define IN_DIM 256
#define HID 128
#define MIDW 192
#define NP 4
#define NCH 5
#define DEG 32
#define E_D (ND*DEG)
#define E_Z (NZ*DEG)

typedef __hip_bfloat16 bf16;
typedef __attribute__((ext_vector_type(8))) short s8v;
typedef __attribute__((ext_vector_type(4))) float f4v;

static __device__ __forceinline__ unsigned short f2bf(float x){
  bf16 b = __float2bfloat16(x);
  return *reinterpret_cast<unsigned short*>(&b);
}
static __device__ __forceinline__ uint packbf2(float a, float b){
  return (uint)f2bf(a) | ((uint)f2bf(b) << 16);
}
static __device__ __forceinline__ void gload16(const void* g, void* l){
  __builtin_amdgcn_global_load_lds(
      (const __attribute__((address_space(1))) unsigned int*)g,
      (__attribute__((address_space(3))) unsigned int*)l, 16, 0, 0);
}

// ---------------- CSR build (drug+disease merged) ----------------
__global__ void k_count(const int* __restrict__ src_d, int* __restrict__ deg_d,
                        const int* __restrict__ src_z, int* __restrict__ deg_z){
  long i = (long)blockIdx.x*blockDim.x + threadIdx.x;
  if (i < (long)NP*E_D){
    int m = (int)(i / E_D);
    atomicAdd(&deg_d[m*ND + src_d[i]], 1);
  } else {
    long j = i - (long)NP*E_D;
    int m = (int)(j / E_Z);
    atomicAdd(&deg_z[m*NZ + src_z[j]], 1);
  }
}

__global__ __launch_bounds__(256) void k_scan(const int* __restrict__ deg_d, int* __restrict__ off_d,
                                              const int* __restrict__ deg_z, int* __restrict__ off_z){
  int b = blockIdx.x;
  const int* d; int* o; int n;
  if (b < NP){ d = deg_d + (long)b*ND; o = off_d + (long)b*(ND+1); n = ND; }
  else { int m = b-NP; d = deg_z + (long)m*NZ; o = off_z + (long)m*(NZ+1); n = NZ; }
  int t = threadIdx.x, lane = t&63, wv = t>>6;
  __shared__ int wsum[4];
  __shared__ int carry;
  if (t==0) carry = 0;
  __syncthreads();
  for (int base=0; base<n; base+=256){
    int v = d[base+t];
    int x = v;
    #pragma unroll
    for (int s=1; s<64; s<<=1){
      int u = __shfl_up(x, s, 64);
      if (lane >= s) x += u;
    }
    if (lane==63) wsum[wv] = x;
    __syncthreads();
    int wo = 0;
    for (int w=0; w<wv; w++) wo += wsum[w];
    int c = carry;
    o[base+t] = c + wo + x - v;
    __syncthreads();
    if (t==255) carry = c + wo + x;
  }
  __syncthreads();
  if (t==0) o[n] = carry;
}

__global__ void k_scatter(const int* __restrict__ src_d, const int* __restrict__ dst_d,
                          const int* __restrict__ off_d, int* __restrict__ cur_d, int* __restrict__ csr_d,
                          const int* __restrict__ src_z, const int* __restrict__ dst_z,
                          const int* __restrict__ off_z, int* __restrict__ cur_z, int* __restrict__ csr_z){
  long i = (long)blockIdx.x*blockDim.x + threadIdx.x;
  if (i < (long)NP*E_D){
    int m = (int)(i / E_D);
    int s = src_d[i];
    int pos = atomicAdd(&cur_d[m*ND + s], 1);
    csr_d[(long)m*E_D + off_d[(long)m*(ND+1) + s] + pos] = dst_d[i];
  } else {
    long j = i - (long)NP*E_D;
    int m = (int)(j / E_Z);
    int s = src_z[j];
    int pos = atomicAdd(&cur_z[m*NZ + s], 1);
    csr_z[(long)m*E_Z + off_z[(long)m*(NZ+1) + s] + pos] = dst_z[j];
  }
}

// ---------------- mega prep ----------------
static __device__ __forceinline__ void tpz(const float* __restrict__ in, bf16* __restrict__ out,
                                           int rows, int cols, long idx){
  int per = rows*cols;
  int b = (int)(idx / per);
  int rem = (int)(idx - (long)b*per);
  int r = rem / cols, c = rem - r*cols;
  out[(long)b*per + (long)c*rows + r] = __float2bfloat16(in[idx]);
}

#define PB0 2048
#define PB1 (PB0+1024)
#define PB2 (PB1+960)
#define PB3 (PB2+960)
#define PB4 (PB3+720)
#define PB5 (PB4+720)
#define PB6 (PB5+480)
#define PB7 (PB6+480)
#define PB8 (PB7+128)
#define PB9 (PB8+128)
#define PB10 (PB9+320)
#define PB11 (PB10+1)

__global__ __launch_bounds__(256) void k_prep(
    const float* feat_d, const float* feat_z, bf16* featb_d, bf16* featb_z,
    const float* dW1, const float* dW2, const float* dW3,
    const float* zW1, const float* zW2, const float* zW3,
    const float* Wq_d, const float* Wk_d, const float* Wq_z, const float* Wk_z,
    const float* Wdec,
    bf16* w1t_d, bf16* w2t_d, bf16* w3t_d, bf16* w1t_z, bf16* w2t_z, bf16* w3t_z,
    bf16* qkw_d, bf16* qkw_z, bf16* wdect,
    const float* bq_d, const float* bk_d, const float* bq_z, const float* bk_z,
    float* qkb_d, float* qkb_z, const float* wattn, float* wsm)
{
  int b = blockIdx.x, t = threadIdx.x;
  if (b < PB0){
    long i4 = (long)b*256 + t;
    float4 v = ((const float4*)feat_d)[i4];
    ushort4 o; o.x=f2bf(v.x); o.y=f2bf(v.y); o.z=f2bf(v.z); o.w=f2bf(v.w);
    ((ushort4*)featb_d)[i4] = o;
  } else if (b < PB1){
    long i4 = (long)(b-PB0)*256 + t;
    float4 v = ((const float4*)feat_z)[i4];
    ushort4 o; o.x=f2bf(v.x); o.y=f2bf(v.y); o.z=f2bf(v.z); o.w=f2bf(v.w);
    ((ushort4*)featb_z)[i4] = o;
  } else if (b < PB2){ tpz(dW1, w1t_d, IN_DIM, MIDW, (long)(b-PB1)*256 + t); }
  else if (b < PB3){ tpz(zW1, w1t_z, IN_DIM, MIDW, (long)(b-PB2)*256 + t); }
  else if (b < PB4){ tpz(dW2, w2t_d, MIDW, MIDW, (long)(b-PB3)*256 + t); }
  else if (b < PB5){ tpz(zW2, w2t_z, MIDW, MIDW, (long)(b-PB4)*256 + t); }
  else if (b < PB6){ tpz(dW3, w3t_d, MIDW, HID, (long)(b-PB5)*256 + t); }
  else if (b < PB7){ tpz(zW3, w3t_z, MIDW, HID, (long)(b-PB6)*256 + t); }
  else if (b < PB8){
    long idx = (long)(b-PB7)*256 + t;
    if (idx < 16384) tpz(Wq_d, qkw_d, HID, HID, idx);
    else tpz(Wk_d, qkw_d + 16384, HID, HID, idx - 16384);
  } else if (b < PB9){
    long idx = (long)(b-PB8)*256 + t;
    if (idx < 16384) tpz(Wq_z, qkw_z, HID, HID, idx);
    else tpz(Wk_z, qkw_z + 16384, HID, HID, idx - 16384);
  } else if (b < PB10){ tpz(Wdec, wdect, HID, HID, (long)(b-PB9)*256 + t); }
  else {
    if (t < 128){ qkb_d[t] = bq_d[t]; qkb_z[t] = bq_z[t]; }
    else { qkb_d[t] = bk_d[t-128]; qkb_z[t] = bk_z[t-128]; }
    if (t == 0){
      float mx = wattn[0];
      for (int i=1;i<NCH;i++) mx = fmaxf(mx, wattn[i]);
      float e[NCH], s=0.f;
      for (int i=0;i<NCH;i++){ e[i]=expf(wattn[i]-mx); s+=e[i]; }
      for (int i=0;i<NCH;i++) wsm[i]=e[i]/s;
    }
  }
}

// ---------------- aggregation (drug+disease merged, 4-edge unroll) ----------------
__global__ __launch_bounds__(256) void k_agg2(
    const int* __restrict__ csr_d, const int* __restrict__ off_d, const float* __restrict__ bias_d,
    const bf16* __restrict__ Y_d, bf16* __restrict__ h1_d,
    const int* __restrict__ csr_z, const int* __restrict__ off_z, const float* __restrict__ bias_z,
    const bf16* __restrict__ Y_z, bf16* __restrict__ h1_z)
{
  int wid = (blockIdx.x*256 + threadIdx.x) >> 6;
  int lane = threadIdx.x & 63;
  const int *csr, *off; const float* bias; const uint* Yb; bf16* h1; int n, E, m;
  if (wid < NP*ND){
    m = wid >> 13; int s0 = wid & (ND-1);
    csr = csr_d; off = off_d; bias = bias_d; h1 = h1_d; n = ND; E = E_D;
    Yb = (const uint*)Y_d + (long)m*ND*96;
    wid = s0;
  } else {
    int w2 = wid - NP*ND;
    m = w2 >> 12; int s0 = w2 & (NZ-1);
    csr = csr_z; off = off_z; bias = bias_z; h1 = h1_z; n = NZ; E = E_Z;
    Yb = (const uint*)Y_z + (long)m*NZ*96;
    wid = s0;
  }
  int s = wid;
  int o0 = off[(long)m*(n+1)+s], o1 = off[(long)m*(n+1)+s+1];
  const int* lst = csr + (long)m*E;
  bool hi = lane < 32;
  float a0=0.f,a1=0.f,a2=0.f,a3=0.f;
  int i = o0;
  for (; i+3 < o1; i += 4){
    const uint* r0 = Yb + (long)lst[i]*96;
    const uint* r1 = Yb + (long)lst[i+1]*96;
    const uint* r2 = Yb + (long)lst[i+2]*96;
    const uint* r3 = Yb + (long)lst[i+3]*96;
    uint w0 = r0[lane], w1 = r1[lane], w2 = r2[lane], w3 = r3[lane];
    uint v0 = hi ? r0[64+lane] : 0u;
    uint v1 = hi ? r1[64+lane] : 0u;
    uint v2 = hi ? r2[64+lane] : 0u;
    uint v3 = hi ? r3[64+lane] : 0u;
    a0 += __uint_as_float(w0<<16) + __uint_as_float(w1<<16) + __uint_as_float(w2<<16) + __uint_as_float(w3<<16);
    a1 += __uint_as_float(w0&0xffff0000u) + __uint_as_float(w1&0xffff0000u) + __uint_as_float(w2&0xffff0000u) + __uint_as_float(w3&0xffff0000u);
    a2 += __uint_as_float(v0<<16) + __uint_as_float(v1<<16) + __uint_as_float(v2<<16) + __uint_as_float(v3<<16);
    a3 += __uint_as_float(v0&0xffff0000u) + __uint_as_float(v1&0xffff0000u) + __uint_as_float(v2&0xffff0000u) + __uint_as_float(v3&0xffff0000u);
  }
  for (; i < o1; i++){
    const uint* r0 = Yb + (long)lst[i]*96;
    uint w0 = r0[lane];
    uint v0 = hi ? r0[64+lane] : 0u;
    a0 += __uint_as_float(w0<<16);
    a1 += __uint_as_float(w0&0xffff0000u);
    a2 += __uint_as_float(v0<<16);
    a3 += __uint_as_float(v0&0xffff0000u);
  }
  float inv = 1.0f / fmaxf((float)(o1-o0), 1.0f);
  const float* bb = bias + (m+1)*MIDW;
  float2 b0 = *(const float2*)(bb + 2*lane);
  uint* hrow = (uint*)((short*)h1 + ((long)(m+1)*n + s)*MIDW);
  hrow[lane] = packbf2(fmaxf(a0*inv + b0.x, 0.f), fmaxf(a1*inv + b0.y, 0.f));
  if (hi){
    float2 b1v = *(const float2*)(bb + 128 + 2*lane);
    hrow[64+lane] = packbf2(fmaxf(a2*inv + b1v.x, 0.f), fmaxf(a3*inv + b1v.y, 0.f));
  }
}

// ---------------- batched bf16 GEMM (two param sets, z-split), 128x64 tile ----------------
struct GemmP {
  const bf16* A; const bf16* BT; const float* bias; bf16* out;
  const float* scale; const float* rowsc;
  long rs_moff, a_moff, out_rstride, out_moff;
  int K, N, nrows;
};

template<bool RELU, bool HAS_SCALE, bool ROWSC>
__global__ __launch_bounds__(256) void k_gemm(GemmP P0, GemmP P1, int zsplit)
{
  const GemmP& p = ((int)blockIdx.z < zsplit) ? P0 : P1;
  int m = ((int)blockIdx.z < zsplit) ? blockIdx.z : blockIdx.z - zsplit;
  long row0 = (long)blockIdx.x*128;
  if (row0 >= p.nrows) return;
  int col0 = blockIdx.y*64;
  if (col0 >= p.N) return;
  __shared__ short As[128*40];
  __shared__ short Bs[64*40];
  int t = threadIdx.x;
  const short* Ag = (const short*)p.A + m*p.a_moff;
  const short* Bg = (const short*)p.BT + (long)m*p.N*p.K;
  int lane = t&63, wv = t>>6;
  int l15 = lane&15, kof = (lane>>4)*8;
  int K = p.K;
  f4v acc[2][4] = {};
  for (int kk=0; kk<K; kk+=32){
    __syncthreads();
    #pragma unroll
    for (int j=0;j<2;j++){
      int c = t + j*256;
      int row = c>>2, sub = c&3;
      *(s8v*)(&As[row*40 + sub*8]) = *(const s8v*)(Ag + (row0+row)*K + kk + sub*8);
    }
    { int row = t>>2, sub = t&3;
      *(s8v*)(&Bs[row*40 + sub*8]) = *(const s8v*)(Bg + (long)(col0+row)*K + kk + sub*8); }
    __syncthreads();
    s8v af[2], bfr[4];
    #pragma unroll
    for (int i2=0;i2<2;i2++) af[i2] = *(const s8v*)(&As[(wv*32 + i2*16 + l15)*40 + kof]);
    #pragma unroll
    for (int j2=0;j2<4;j2++) bfr[j2] = *(const s8v*)(&Bs[(j2*16 + l15)*40 + kof]);
    #pragma unroll
    for (int i2=0;i2<2;i2++)
      #pragma unroll
      for (int j2=0;j2<4;j2++)
        acc[i2][j2] = __builtin_amdgcn_mfma_f32_16x16x32_bf16(af[i2], bfr[j2], acc[i2][j2],0,0,0);
  }
  float sc = HAS_SCALE ? p.scale[m] : 1.0f;
  #pragma unroll
  for (int i2=0;i2<2;i2++){
    #pragma unroll
    for (int j2=0;j2<4;j2++){
      int col = col0 + j2*16 + l15;
      float bv = p.bias ? p.bias[m*p.N + col] : 0.f;
      #pragma unroll
      for (int r=0;r<4;r++){
        long row = row0 + wv*32 + i2*16 + (lane>>4)*4 + r;
        float v = acc[i2][j2][r] + bv;
        if (RELU) v = fmaxf(v, 0.f);
        v *= sc;
        if (ROWSC) v *= p.rowsc[m*p.rs_moff + row];
        p.out[m*p.out_moff + row*p.out_rstride + col] = __float2bfloat16(v);
      }
    }
  }
}

// ---------------- per-node metapath attention (merged d+z, one wave per node) ----------------
__global__ __launch_bounds__(64) void k_attn(
    const bf16* __restrict__ p_d, const bf16* __restrict__ qk_d, const float* __restrict__ beta_d,
    bf16* __restrict__ o_d,
    const bf16* __restrict__ p_z, const bf16* __restrict__ qk_z, const float* __restrict__ beta_z,
    bf16* __restrict__ o_z)
{
  int node = blockIdx.x; int t = threadIdx.x;
  const bf16 *pp, *qrow; bf16* outp; const float* betap;
  if (node < ND){
    pp = p_d + (long)node*(NCH*HID); qrow = qk_d + (long)node*NCH*256;
    outp = o_d + (long)node*(NCH*HID); betap = beta_d;
  } else {
    int nz = node - ND;
    pp = p_z + (long)nz*(NCH*HID); qrow = qk_z + (long)nz*NCH*256;
    outp = o_z + (long)nz*(NCH*HID); betap = beta_z;
  }
  __shared__ float pl[NCH*HID], ql[NCH*HID], kl[NCH*HID];
  __shared__ float lg[25], at[25];
  const uint* pu = (const uint*)pp;
  const uint* qu = (const uint*)qrow;
  for (int i=t; i<NCH*HID/2; i+=64){      // 320 dwords
    uint w = pu[i];
    pl[2*i]   = __uint_as_float(w<<16);
    pl[2*i+1] = __uint_as_float(w & 0xffff0000u);
  }
  for (int i=t; i<NCH*256/2; i+=64){      // 640 dwords: per mm, 64 Q-dwords then 64 K-dwords
    uint w = qu[i];
    int mm = i>>7, rest = i&127;
    float lo = __uint_as_float(w<<16), hv = __uint_as_float(w & 0xffff0000u);
    if (rest < 64){ ql[mm*HID + 2*rest] = lo; ql[mm*HID + 2*rest+1] = hv; }
    else { int r2 = rest-64; kl[mm*HID + 2*r2] = lo; kl[mm*HID + 2*r2+1] = hv; }
  }
  __syncthreads();
  if (t < 50){
    int pr = t>>1, sub = t&1;
    int mi = pr/5, ki = pr - 5*mi;
    float s = 0.f;
    int h0 = sub*64;
    for (int h=h0; h<h0+64; h++) s += ql[mi*HID+h]*kl[ki*HID+h];
    s += __shfl_xor(s, 1);
    if (sub==0) lg[pr] = s;
  }
  __syncthreads();
  if (t < 5){
    float mx = lg[t*5];
    for (int j=1;j<5;j++) mx = fmaxf(mx, lg[t*5+j]);
    float e[5], su=0.f;
    for (int j=0;j<5;j++){ e[j] = expf(lg[t*5+j]-mx); su += e[j]; }
    for (int j=0;j<5;j++) at[t*5+j] = e[j]/su;
  }
  __syncthreads();
  float bt = betap[0];
  for (int i=t; i<NCH*HID; i+=64){
    int mm = i>>7, h = i&127;
    float s = 0.f;
    #pragma unroll
    for (int k2=0;k2<5;k2++) s += at[mm*5+k2]*pl[k2*HID+h];
    outp[i] = __float2bfloat16(pl[i] + bt*s);
  }
}

// ---------------- final GEMM: out(ND,NZ)=A(ND,640)@B(NZ,640)^T ----------------
// m97 structure: global_load_lds staging (linear LDS dest, inverse-swizzled global src),
// XOR-swizzled ds_read (0 conflicts), BK=64, 128x128 tile, 4 waves.
__global__ __launch_bounds__(256) void k_gemm_final(
    const bf16* __restrict__ Aout, const bf16* __restrict__ Bb, float* __restrict__ out)
{
  __shared__ short As[128*64];
  __shared__ short Bs[128*64];
  int t = threadIdx.x;
  int lane = t&63, wv=t>>6, wr=wv>>1, wc=wv&1;
  int row0 = blockIdx.x*128, col0 = blockIdx.y*128;
  const short* Ag = (const short*)Aout;
  const short* Bg = (const short*)Bb;
  int l15 = lane&15, hi = lane>>4;
  // staging: instr j covers rows j*32 + (t>>3); global seg pre-swizzled so linear LDS
  // dest ends up holding seg' = seg ^ (row&7) at slot seg (read side XORs identically).
  int srow = t>>3;
  int sseg = (t&7) ^ (srow&7);
  f4v acc[4][4] = {};
  for (int kk=0; kk<NCH*HID; kk+=64){
    int mch = kk>>7, h0 = kk&127;
    __syncthreads();    // previous iteration's reads complete before overwrite
    #pragma unroll
    for (int j=0;j<4;j++){
      int row = j*32 + srow;
      gload16(Ag + ((long)mch*ND + row0+row)*HID + h0 + sseg*8,
              (char*)As + ((j*256 + t)<<4));
      gload16(Bg + (long)(col0+row)*(NCH*HID) + kk + sseg*8,
              (char*)Bs + ((j*256 + t)<<4));
    }
    asm volatile("s_waitcnt vmcnt(0)" ::: "memory");
    __syncthreads();
    #pragma unroll
    for (int sl=0; sl<2; sl++){
      s8v af[4], bg[4];
      #pragma unroll
      for (int i=0;i<4;i++){
        int ra = wr*64 + i*16 + l15;
        af[i] = *(const s8v*)(&As[ra*64 + (((sl*4+hi) ^ (ra&7))*8)]);
        int rb = wc*64 + i*16 + l15;
        bg[i] = *(const s8v*)(&Bs[rb*64 + (((sl*4+hi) ^ (rb&7))*8)]);
      }
      #pragma unroll
      for (int mi=0;mi<4;mi++)
        #pragma unroll
        for (int ni=0;ni<4;ni++)
          acc[mi][ni] = __builtin_amdgcn_mfma_f32_16x16x32_bf16(af[mi], bg[ni], acc[mi][ni],0,0,0);
    }
  }
  #pragma unroll
  for (int mi=0;mi<4;mi++){
    #pragma unroll
    for (int ni=0;ni<4;ni++){
      int col = col0 + wc*64 + ni*16 + l15;
      #pragma unroll
      for (int r=0;r<4;r++){
        int row = row0 + wr*64 + mi*16 + hi*4 + r;
        out[(long)row*NZ + col] = acc[mi][ni][r];
      }
    }
  }
}

extern "C" void kernel_launch(void* const* d_in, const int* in_sizes, int n_in,
                              void* d_out, int out_size, void* d_ws, size_t ws_size,
                              hipStream_t stream)
{
  (void)in_sizes; (void)n_in; (void)out_size;
  const float* feat_d = (const float*)d_in[0];
  const float* feat_z = (const float*)d_in[1];
  const float* att_d  = (const float*)d_in[2];
  const float* att_z  = (const float*)d_in[3];
  const int* src_d = (const int*)d_in[4];
  const int* dst_d = (const int*)d_in[5];
  const int* src_z = (const int*)d_in[6];
  const int* dst_z = (const int*)d_in[7];
  const float* dW1=(const float*)d_in[8];  const float* db1=(const float*)d_in[9];
  const float* dW2=(const float*)d_in[10]; const float* db2=(const float*)d_in[11];
  const float* dW3=(const float*)d_in[12]; const float* db3=(const float*)d_in[13];
  const float* Wq_d=(const float*)d_in[14]; const float* bq_d=(const float*)d_in[15];
  const float* Wk_d=(const float*)d_in[16]; const float* bk_d=(const float*)d_in[17];
  const float* beta_d=(const float*)d_in[18];
  const float* zW1=(const float*)d_in[19]; const float* zb1=(const float*)d_in[20];
  const float* zW2=(const float*)d_in[21]; const float* zb2=(const float*)d_in[22];
  const float* zW3=(const float*)d_in[23]; const float* zb3=(const float*)d_in[24];
  const float* Wq_z=(const float*)d_in[25]; const float* bq_z=(const float*)d_in[26];
  const float* Wk_z=(const float*)d_in[27]; const float* bk_z=(const float*)d_in[28];
  const float* beta_z=(const float*)d_in[29];
  const float* wattn=(const float*)d_in[30];
  const float* Wdec=(const float*)d_in[31]; const float* bdec=(const float*)d_in[32];

  char* ws = (char*)d_ws;
  size_t o = 0;
  auto alloc = [&](size_t bytes)->char*{
    size_t r = (o + 255) & ~(size_t)255;
    o = r + bytes;
    return ws + r;
  };
  bf16* featb_d = (bf16*)alloc((size_t)ND*IN_DIM*2);
  bf16* featb_z = (bf16*)alloc((size_t)NZ*IN_DIM*2);
  bf16* Y_d = (bf16*)alloc((size_t)NP*ND*MIDW*2);
  bf16* Y_z = (bf16*)alloc((size_t)NP*NZ*MIDW*2);
  bf16* h1_d = (bf16*)alloc((size_t)NCH*ND*MIDW*2);
  bf16* h2_d = (bf16*)alloc((size_t)NCH*ND*MIDW*2);
  bf16* pbuf_d = (bf16*)alloc((size_t)ND*NCH*HID*2);
  bf16* qk_d = (bf16*)alloc((size_t)ND*NCH*256*2);
  bf16* h1_z = (bf16*)alloc((size_t)NCH*NZ*MIDW*2);
  bf16* h2_z = (bf16*)alloc((size_t)NCH*NZ*MIDW*2);
  bf16* pbuf_z = (bf16*)alloc((size_t)NZ*NCH*HID*2);
  int* csr_d = (int*)alloc((size_t)NP*E_D*4);
  int* csr_z = (int*)alloc((size_t)NP*E_Z*4);
  int* degcur = (int*)alloc((size_t)(NP*ND*2 + NP*NZ*2)*4);
  int* deg_d = degcur;
  int* cur_d = deg_d + NP*ND;
  int* deg_z = cur_d + NP*ND;
  int* cur_z = deg_z + NP*NZ;
  int* off_d = (int*)alloc((size_t)NP*(ND+1)*4);
  int* off_z = (int*)alloc((size_t)NP*(NZ+1)*4);
  bf16* w1t_d = (bf16*)alloc((size_t)NCH*MIDW*IN_DIM*2);
  bf16* w2t_d = (bf16*)alloc((size_t)NCH*MIDW*MIDW*2);
  bf16* w3t_d = (bf16*)alloc((size_t)NCH*HID*MIDW*2);
  bf16* w1t_z = (bf16*)alloc((size_t)NCH*MIDW*IN_DIM*2);
  bf16* w2t_z = (bf16*)alloc((size_t)NCH*MIDW*MIDW*2);
  bf16* w3t_z = (bf16*)alloc((size_t)NCH*HID*MIDW*2);
  bf16* qkw_d = (bf16*)alloc((size_t)2*HID*HID*2);
  bf16* qkw_z = (bf16*)alloc((size_t)2*HID*HID*2);
  bf16* wdect = (bf16*)alloc((size_t)NCH*HID*HID*2);
  float* qkb_d = (float*)alloc((size_t)2*HID*4);
  float* qkb_z = (float*)alloc((size_t)2*HID*4);
  float* wsm   = (float*)alloc((size_t)NCH*4);
  bf16* out_d = h1_d;
  bf16* out_z = h1_z;
  bf16* qk_z  = Y_d;
  bf16* Bbig  = Y_z;
  if (ws_size < o) return;

  hipMemsetAsync(degcur, 0, (size_t)(NP*ND*2 + NP*NZ*2)*4, stream);
  k_prep<<<PB11, 256, 0, stream>>>(feat_d, feat_z, featb_d, featb_z,
      dW1, dW2, dW3, zW1, zW2, zW3, Wq_d, Wk_d, Wq_z, Wk_z, Wdec,
      w1t_d, w2t_d, w3t_d, w1t_z, w2t_z, w3t_z, qkw_d, qkw_z, wdect,
      bq_d, bk_d, bq_z, bk_z, qkb_d, qkb_z, wattn, wsm);
  k_count<<<(NP*E_D + NP*E_Z)/256, 256, 0, stream>>>(src_d, deg_d, src_z, deg_z);
  k_scan<<<2*NP, 256, 0, stream>>>(deg_d, off_d, deg_z, off_z);
  k_scatter<<<(NP*E_D + NP*E_Z)/256, 256, 0, stream>>>(src_d, dst_d, off_d, cur_d, csr_d,
                                                       src_z, dst_z, off_z, cur_z, csr_z);

  {
    GemmP pd = {featb_d, w1t_d, db1, h1_d, nullptr, nullptr, 0, 0, MIDW, 0, IN_DIM, MIDW, ND};
    GemmP pz = {featb_z, w1t_z, zb1, h1_z, nullptr, nullptr, 0, 0, MIDW, 0, IN_DIM, MIDW, NZ};
    k_gemm<true,false,false><<<dim3(64, 3, 2), 256, 0, stream>>>(pd, pz, 1);
  }
  {
    GemmP pd = {featb_d, w1t_d + MIDW*IN_DIM, nullptr, Y_d, nullptr, att_d, ND, 0, MIDW, (long)ND*MIDW, IN_DIM, MIDW, ND};
    GemmP pz = {featb_z, w1t_z + MIDW*IN_DIM, nullptr, Y_z, nullptr, att_z, NZ, 0, MIDW, (long)NZ*MIDW, IN_DIM, MIDW, NZ};
    k_gemm<false,false,true><<<dim3(64, 3, 8), 256, 0, stream>>>(pd, pz, 4);
  }
  k_agg2<<<(NP*ND + NP*NZ)/4, 256, 0, stream>>>(csr_d, off_d, db1, Y_d, h1_d,
                                                csr_z, off_z, zb1, Y_z, h1_z);
  {
    GemmP pd = {h1_d, w2t_d, db2, h2_d, nullptr, nullptr, 0, (long)ND*MIDW, MIDW, (long)ND*MIDW, MIDW, MIDW, ND};
    GemmP pz = {h1_z, w2t_z, zb2, h2_z, nullptr, nullptr, 0, (long)NZ*MIDW, MIDW, (long)NZ*MIDW, MIDW, MIDW, NZ};
    k_gemm<true,false,false><<<dim3(64, 3, 10), 256, 0, stream>>>(pd, pz, 5);
  }
  {
    GemmP pd = {h2_d, w3t_d, db3, pbuf_d, nullptr, nullptr, 0, (long)ND*MIDW, (long)NCH*HID, HID, MIDW, HID, ND};
    GemmP pz = {h2_z, w3t_z, zb3, pbuf_z, nullptr, nullptr, 0, (long)NZ*MIDW, (long)NCH*HID, HID, MIDW, HID, NZ};
    k_gemm<false,false,false><<<dim3(64, 2, 10), 256, 0, stream>>>(pd, pz, 5);
  }
  {
    GemmP pd = {pbuf_d, qkw_d, qkb_d, qk_d, nullptr, nullptr, 0, 0, 256, 0, HID, 256, ND*NCH};
    GemmP pz = {pbuf_z, qkw_z, qkb_z, qk_z, nullptr, nullptr, 0, 0, 256, 0, HID, 256, NZ*NCH};
    k_gemm<false,false,false><<<dim3(320, 4, 2), 256, 0, stream>>>(pd, pz, 1);
  }
  k_attn<<<ND + NZ, 64, 0, stream>>>(pbuf_d, qk_d, beta_d, out_d,
                                     pbuf_z, qk_z, beta_z, out_z);
  {
    GemmP pz = {out_z, wdect, bdec, Bbig, wsm, nullptr, 0, (long)NZ*HID, (long)NCH*HID, HID, HID, HID, NZ};
    k_gemm<false,true,false><<<dim3(32, 2, 5), 256, 0, stream>>>(pz, pz, 5);
  }
  k_gemm_final<<<dim3(64, 32), 256, 0, stream>>>(out_d, Bbig, (float*)d_out);
}

// Round 5
// 399.570 us; speedup vs baseline: 1.5445x; 1.0322x over previous
//
#include <hip/hip_runtime.h>
#include <hip/hip_bf16.h>

#define ND 8192
#define NZ 4096
#define IN_DIM 256
#define HID 128
#define MIDW 192
#define NP 4
#define NCH 5
#define DEG 32
#define E_D (ND*DEG)
#define E_Z (NZ*DEG)

typedef __hip_bfloat16 bf16;
typedef __attribute__((ext_vector_type(8))) short s8v;
typedef __attribute__((ext_vector_type(4))) float f4v;

static __device__ __forceinline__ unsigned short f2bf(float x){
  bf16 b = __float2bfloat16(x);
  return *reinterpret_cast<unsigned short*>(&b);
}
static __device__ __forceinline__ uint packbf2(float a, float b){
  return (uint)f2bf(a) | ((uint)f2bf(b) << 16);
}
static __device__ __forceinline__ float bfl(uint w){ return __uint_as_float(w<<16); }
static __device__ __forceinline__ float bfh(uint w){ return __uint_as_float(w & 0xffff0000u); }
static __device__ __forceinline__ void gload16(const void* g, void* l){
  __builtin_amdgcn_global_load_lds(
      (const __attribute__((address_space(1))) unsigned int*)g,
      (__attribute__((address_space(3))) unsigned int*)l, 16, 0, 0);
}

// ---------------- CSR build (drug+disease merged) ----------------
__global__ void k_count(const int* __restrict__ src_d, int* __restrict__ deg_d,
                        const int* __restrict__ src_z, int* __restrict__ deg_z){
  long i = (long)blockIdx.x*blockDim.x + threadIdx.x;
  if (i < (long)NP*E_D){
    int m = (int)(i / E_D);
    atomicAdd(&deg_d[m*ND + src_d[i]], 1);
  } else {
    long j = i - (long)NP*E_D;
    int m = (int)(j / E_Z);
    atomicAdd(&deg_z[m*NZ + src_z[j]], 1);
  }
}

__global__ __launch_bounds__(256) void k_scan(const int* __restrict__ deg_d, int* __restrict__ off_d,
                                              const int* __restrict__ deg_z, int* __restrict__ off_z){
  int b = blockIdx.x;
  const int* d; int* o; int n;
  if (b < NP){ d = deg_d + (long)b*ND; o = off_d + (long)b*(ND+1); n = ND; }
  else { int m = b-NP; d = deg_z + (long)m*NZ; o = off_z + (long)m*(NZ+1); n = NZ; }
  int t = threadIdx.x, lane = t&63, wv = t>>6;
  __shared__ int wsum[4];
  __shared__ int carry;
  if (t==0) carry = 0;
  __syncthreads();
  for (int base=0; base<n; base+=256){
    int v = d[base+t];
    int x = v;
    #pragma unroll
    for (int s=1; s<64; s<<=1){
      int u = __shfl_up(x, s, 64);
      if (lane >= s) x += u;
    }
    if (lane==63) wsum[wv] = x;
    __syncthreads();
    int wo = 0;
    for (int w=0; w<wv; w++) wo += wsum[w];
    int c = carry;
    o[base+t] = c + wo + x - v;
    __syncthreads();
    if (t==255) carry = c + wo + x;
  }
  __syncthreads();
  if (t==0) o[n] = carry;
}

__global__ void k_scatter(const int* __restrict__ src_d, const int* __restrict__ dst_d,
                          const int* __restrict__ off_d, int* __restrict__ cur_d, int* __restrict__ csr_d,
                          const int* __restrict__ src_z, const int* __restrict__ dst_z,
                          const int* __restrict__ off_z, int* __restrict__ cur_z, int* __restrict__ csr_z){
  long i = (long)blockIdx.x*blockDim.x + threadIdx.x;
  if (i < (long)NP*E_D){
    int m = (int)(i / E_D);
    int s = src_d[i];
    int pos = atomicAdd(&cur_d[m*ND + s], 1);
    csr_d[(long)m*E_D + off_d[(long)m*(ND+1) + s] + pos] = dst_d[i];
  } else {
    long j = i - (long)NP*E_D;
    int m = (int)(j / E_Z);
    int s = src_z[j];
    int pos = atomicAdd(&cur_z[m*NZ + s], 1);
    csr_z[(long)m*E_Z + off_z[(long)m*(NZ+1) + s] + pos] = dst_z[j];
  }
}

// ---------------- mega prep ----------------
static __device__ __forceinline__ void tpz(const float* __restrict__ in, bf16* __restrict__ out,
                                           int rows, int cols, long idx){
  int per = rows*cols;
  int b = (int)(idx / per);
  int rem = (int)(idx - (long)b*per);
  int r = rem / cols, c = rem - r*cols;
  out[(long)b*per + (long)c*rows + r] = __float2bfloat16(in[idx]);
}

#define PB0 2048
#define PB1 (PB0+1024)
#define PB2 (PB1+960)
#define PB3 (PB2+960)
#define PB4 (PB3+720)
#define PB5 (PB4+720)
#define PB6 (PB5+480)
#define PB7 (PB6+480)
#define PB8 (PB7+256)
#define PB9 (PB8+320)
#define PB10 (PB9+1)

__global__ __launch_bounds__(256) void k_prep(
    const float* feat_d, const float* feat_z, bf16* featb_d, bf16* featb_z,
    const float* dW1, const float* dW2, const float* dW3,
    const float* zW1, const float* zW2, const float* zW3,
    const float* Wq_d, const float* Wk_d, const float* Wq_z, const float* Wk_z,
    const float* Wdec,
    bf16* w1t_d, bf16* w2t_d, bf16* w3t_d, bf16* w1t_z, bf16* w2t_z, bf16* w3t_z,
    bf16* qwb, bf16* kwb, bf16* wdect,
    const float* bq_d, const float* bq_z,
    float* v2v, const float* wattn, float* wsm)
{
  int b = blockIdx.x, t = threadIdx.x;
  if (b < PB0){
    long i4 = (long)b*256 + t;
    float4 v = ((const float4*)feat_d)[i4];
    ushort4 o; o.x=f2bf(v.x); o.y=f2bf(v.y); o.z=f2bf(v.z); o.w=f2bf(v.w);
    ((ushort4*)featb_d)[i4] = o;
  } else if (b < PB1){
    long i4 = (long)(b-PB0)*256 + t;
    float4 v = ((const float4*)feat_z)[i4];
    ushort4 o; o.x=f2bf(v.x); o.y=f2bf(v.y); o.z=f2bf(v.z); o.w=f2bf(v.w);
    ((ushort4*)featb_z)[i4] = o;
  } else if (b < PB2){ tpz(dW1, w1t_d, IN_DIM, MIDW, (long)(b-PB1)*256 + t); }
  else if (b < PB3){ tpz(zW1, w1t_z, IN_DIM, MIDW, (long)(b-PB2)*256 + t); }
  else if (b < PB4){ tpz(dW2, w2t_d, MIDW, MIDW, (long)(b-PB3)*256 + t); }
  else if (b < PB5){ tpz(zW2, w2t_z, MIDW, MIDW, (long)(b-PB4)*256 + t); }
  else if (b < PB6){ tpz(dW3, w3t_d, MIDW, HID, (long)(b-PB5)*256 + t); }
  else if (b < PB7){ tpz(zW3, w3t_z, MIDW, HID, (long)(b-PB6)*256 + t); }
  else if (b < PB8){
    // linear bf16 copies of Wq/Wk for both types: qwb=[d|z], kwb=[d|z]
    long idx = (long)(b-PB7)*256 + t;          // 0..65535
    if (idx < 16384)      qwb[idx] = __float2bfloat16(Wq_d[idx]);
    else if (idx < 32768) qwb[idx] = __float2bfloat16(Wq_z[idx-16384]);
    else if (idx < 49152) kwb[idx-32768] = __float2bfloat16(Wk_d[idx-32768]);
    else                  kwb[idx-32768] = __float2bfloat16(Wk_z[idx-49152]);
  } else if (b < PB9){ tpz(Wdec, wdect, HID, HID, (long)(b-PB8)*256 + t); }
  else {
    // v2[i] = sum_j Wk[i,j]*bq[j]  (softmax-relevant K-side bias projection)
    if (t < 128){
      float s = 0.f;
      for (int j=0;j<HID;j++) s += Wk_d[t*HID+j]*bq_d[j];
      v2v[t] = s;
    } else {
      int tt = t-128;
      float s = 0.f;
      for (int j=0;j<HID;j++) s += Wk_z[tt*HID+j]*bq_z[j];
      v2v[128+tt] = s;
    }
    if (t == 0){
      float mx = wattn[0];
      for (int i=1;i<NCH;i++) mx = fmaxf(mx, wattn[i]);
      float e[NCH], s=0.f;
      for (int i=0;i<NCH;i++){ e[i]=expf(wattn[i]-mx); s+=e[i]; }
      for (int i=0;i<NCH;i++) wsm[i]=e[i]/s;
    }
  }
}

// ---------------- aggregation (merged, shfl-broadcast edge indices) ----------------
__global__ __launch_bounds__(256) void k_agg2(
    const int* __restrict__ csr_d, const int* __restrict__ off_d, const float* __restrict__ bias_d,
    const bf16* __restrict__ Y_d, bf16* __restrict__ h1_d,
    const int* __restrict__ csr_z, const int* __restrict__ off_z, const float* __restrict__ bias_z,
    const bf16* __restrict__ Y_z, bf16* __restrict__ h1_z)
{
  int wid = (blockIdx.x*256 + threadIdx.x) >> 6;
  int lane = threadIdx.x & 63;
  const int *csr, *off; const float* bias; const uint* Yb; bf16* h1; int n, E, m;
  if (wid < NP*ND){
    m = wid >> 13; int s0 = wid & (ND-1);
    csr = csr_d; off = off_d; bias = bias_d; h1 = h1_d; n = ND; E = E_D;
    Yb = (const uint*)Y_d + (long)m*ND*96;
    wid = s0;
  } else {
    int w2 = wid - NP*ND;
    m = w2 >> 12; int s0 = w2 & (NZ-1);
    csr = csr_z; off = off_z; bias = bias_z; h1 = h1_z; n = NZ; E = E_Z;
    Yb = (const uint*)Y_z + (long)m*NZ*96;
    wid = s0;
  }
  int s = wid;
  int o0 = off[(long)m*(n+1)+s], o1 = off[(long)m*(n+1)+s+1];
  int cnt = o1 - o0;
  const int* lp = csr + (long)m*E + o0;
  bool hi2 = lane < 32;
  float a0=0.f,a1=0.f,a2=0.f,a3=0.f;
  for (int base=0; base<cnt; base+=64){
    int rem = cnt - base;
    int idx = (lane < rem) ? lane : (rem-1);
    int e = lp[base + idx];
    int lim = rem < 64 ? rem : 64;
    int j = 0;
    for (; j+1<lim; j+=2){
      int d0 = __shfl(e, j), d1 = __shfl(e, j+1);
      const uint* r0 = Yb + (long)d0*96;
      const uint* r1 = Yb + (long)d1*96;
      uint w0 = r0[lane], w1 = r1[lane];
      uint v0 = hi2 ? r0[64+lane] : 0u;
      uint v1 = hi2 ? r1[64+lane] : 0u;
      a0 += bfl(w0)+bfl(w1); a1 += bfh(w0)+bfh(w1);
      a2 += bfl(v0)+bfl(v1); a3 += bfh(v0)+bfh(v1);
    }
    if (j < lim){
      int d0 = __shfl(e, j);
      const uint* r0 = Yb + (long)d0*96;
      uint w0 = r0[lane];
      uint v0 = hi2 ? r0[64+lane] : 0u;
      a0 += bfl(w0); a1 += bfh(w0);
      a2 += bfl(v0); a3 += bfh(v0);
    }
  }
  float inv = 1.0f / fmaxf((float)cnt, 1.0f);
  const float* bb = bias + (m+1)*MIDW;
  float2 b0 = *(const float2*)(bb + 2*lane);
  uint* hrow = (uint*)((short*)h1 + ((long)(m+1)*n + s)*MIDW);
  hrow[lane] = packbf2(fmaxf(a0*inv + b0.x, 0.f), fmaxf(a1*inv + b0.y, 0.f));
  if (hi2){
    float2 b1v = *(const float2*)(bb + 128 + 2*lane);
    hrow[64+lane] = packbf2(fmaxf(a2*inv + b1v.x, 0.f), fmaxf(a3*inv + b1v.y, 0.f));
  }
}

// ---------------- batched bf16 GEMM (runtime flags), 128x64 tile ----------------
struct GemmP {
  const bf16* A; const bf16* BT; const float* bias; bf16* out;
  const float* scale; const float* rowsc;
  long rs_moff, a_moff, out_rstride, out_moff;
  int K, N, nrows, relu;
};

__global__ __launch_bounds__(256) void k_gemm(GemmP P0, GemmP P1, int zsplit)
{
  const GemmP& p = ((int)blockIdx.z < zsplit) ? P0 : P1;
  int m = ((int)blockIdx.z < zsplit) ? blockIdx.z : blockIdx.z - zsplit;
  long row0 = (long)blockIdx.x*128;
  if (row0 >= p.nrows) return;
  int col0 = blockIdx.y*64;
  if (col0 >= p.N) return;
  __shared__ short As[128*40];
  __shared__ short Bs[64*40];
  int t = threadIdx.x;
  const short* Ag = (const short*)p.A + m*p.a_moff;
  const short* Bg = (const short*)p.BT + (long)m*p.N*p.K;
  int lane = t&63, wv = t>>6;
  int l15 = lane&15, kof = (lane>>4)*8;
  int K = p.K;
  f4v acc[2][4] = {};
  for (int kk=0; kk<K; kk+=32){
    __syncthreads();
    #pragma unroll
    for (int j=0;j<2;j++){
      int c = t + j*256;
      int row = c>>2, sub = c&3;
      *(s8v*)(&As[row*40 + sub*8]) = *(const s8v*)(Ag + (row0+row)*K + kk + sub*8);
    }
    { int row = t>>2, sub = t&3;
      *(s8v*)(&Bs[row*40 + sub*8]) = *(const s8v*)(Bg + (long)(col0+row)*K + kk + sub*8); }
    __syncthreads();
    s8v af[2], bfr[4];
    #pragma unroll
    for (int i2=0;i2<2;i2++) af[i2] = *(const s8v*)(&As[(wv*32 + i2*16 + l15)*40 + kof]);
    #pragma unroll
    for (int j2=0;j2<4;j2++) bfr[j2] = *(const s8v*)(&Bs[(j2*16 + l15)*40 + kof]);
    #pragma unroll
    for (int i2=0;i2<2;i2++)
      #pragma unroll
      for (int j2=0;j2<4;j2++)
        acc[i2][j2] = __builtin_amdgcn_mfma_f32_16x16x32_bf16(af[i2], bfr[j2], acc[i2][j2],0,0,0);
  }
  float sc = p.scale ? p.scale[m] : 1.0f;
  #pragma unroll
  for (int i2=0;i2<2;i2++){
    #pragma unroll
    for (int j2=0;j2<4;j2++){
      int col = col0 + j2*16 + l15;
      float bv = p.bias ? p.bias[m*p.N + col] : 0.f;
      #pragma unroll
      for (int r=0;r<4;r++){
        long row = row0 + wv*32 + i2*16 + (lane>>4)*4 + r;
        float v = acc[i2][j2][r] + bv;
        if (p.relu) v = fmaxf(v, 0.f);
        v *= sc;
        if (p.rowsc) v *= p.rowsc[m*p.rs_moff + row];
        p.out[m*p.out_moff + row*p.out_rstride + col] = __float2bfloat16(v);
      }
    }
  }
}

// ---------------- fused MLP layers 2+3: p = relu(h1@W2+b2)@W3 + b3 ----------------
struct MlpP { const bf16* h1; const bf16* w2t; const float* b2;
              const bf16* w3t; const float* b3; bf16* pout; int n; };

__global__ __launch_bounds__(256) void k_mlp23(MlpP P0, MlpP P1, int zsplit)
{
  const MlpP& p = ((int)blockIdx.z < zsplit) ? P0 : P1;
  int m = ((int)blockIdx.z < zsplit) ? blockIdx.z : blockIdx.z - zsplit;
  int row0 = blockIdx.x*128;
  if (row0 >= p.n) return;
  __shared__ short h2s[128*200];      // padded stride 200 (100 dwords ≡ 4 mod 32: 2-way max)
  __shared__ short As[128*40];
  __shared__ short Bs[192*40];
  int t = threadIdx.x, lane = t&63, wv = t>>6;
  int l15 = lane&15, hi = lane>>4, kof = hi*8;
  const short* Ag = (const short*)p.h1 + ((long)m*p.n + row0)*MIDW;
  const short* Bg = (const short*)p.w2t + (long)m*MIDW*MIDW;
  f4v accA[2][12] = {};
  for (int kk=0; kk<MIDW; kk+=32){
    __syncthreads();
    #pragma unroll
    for (int j=0;j<2;j++){
      int c = t + j*256;
      int row = c>>2, sub = c&3;
      *(s8v*)(&As[row*40 + sub*8]) = *(const s8v*)(Ag + (long)row*MIDW + kk + sub*8);
    }
    #pragma unroll
    for (int j=0;j<3;j++){
      int c = t + j*256;
      int row = c>>2, sub = c&3;
      *(s8v*)(&Bs[row*40 + sub*8]) = *(const s8v*)(Bg + (long)row*MIDW + kk + sub*8);
    }
    __syncthreads();
    s8v af[2], bfr[12];
    #pragma unroll
    for (int i2=0;i2<2;i2++) af[i2] = *(const s8v*)(&As[(wv*32 + i2*16 + l15)*40 + kof]);
    #pragma unroll
    for (int j2=0;j2<12;j2++) bfr[j2] = *(const s8v*)(&Bs[(j2*16 + l15)*40 + kof]);
    #pragma unroll
    for (int i2=0;i2<2;i2++)
      #pragma unroll
      for (int j2=0;j2<12;j2++)
        accA[i2][j2] = __builtin_amdgcn_mfma_f32_16x16x32_bf16(af[i2], bfr[j2], accA[i2][j2],0,0,0);
  }
  // bias + relu -> h2s (bf16)
  float b2l[12];
  #pragma unroll
  for (int j2=0;j2<12;j2++) b2l[j2] = p.b2[m*MIDW + j2*16 + l15];
  #pragma unroll
  for (int i2=0;i2<2;i2++)
    #pragma unroll
    for (int j2=0;j2<12;j2++)
      #pragma unroll
      for (int r=0;r<4;r++){
        int rl = wv*32 + i2*16 + hi*4 + r;
        float v = fmaxf(accA[i2][j2][r] + b2l[j2], 0.f);
        h2s[rl*200 + j2*16 + l15] = (short)f2bf(v);
      }
  // phase B: p = h2s @ w3t^T
  const short* Cg = (const short*)p.w3t + (long)m*HID*MIDW;
  f4v accB[2][8] = {};
  for (int kk=0; kk<MIDW; kk+=32){
    __syncthreads();
    #pragma unroll
    for (int j=0;j<2;j++){
      int c = t + j*256;
      int row = c>>2, sub = c&3;
      *(s8v*)(&Bs[row*40 + sub*8]) = *(const s8v*)(Cg + (long)row*MIDW + kk + sub*8);
    }
    __syncthreads();
    s8v af[2], bfr[8];
    #pragma unroll
    for (int i2=0;i2<2;i2++) af[i2] = *(const s8v*)(&h2s[(wv*32 + i2*16 + l15)*200 + kk + kof]);
    #pragma unroll
    for (int j2=0;j2<8;j2++) bfr[j2] = *(const s8v*)(&Bs[(j2*16 + l15)*40 + kof]);
    #pragma unroll
    for (int i2=0;i2<2;i2++)
      #pragma unroll
      for (int j2=0;j2<8;j2++)
        accB[i2][j2] = __builtin_amdgcn_mfma_f32_16x16x32_bf16(af[i2], bfr[j2], accB[i2][j2],0,0,0);
  }
  #pragma unroll
  for (int j2=0;j2<8;j2++){
    float b3v = p.b3[m*HID + j2*16 + l15];
    #pragma unroll
    for (int i2=0;i2<2;i2++)
      #pragma unroll
      for (int r=0;r<4;r++){
        long row = row0 + wv*32 + i2*16 + hi*4 + r;
        p.pout[row*(NCH*HID) + m*HID + j2*16 + l15] =
            __float2bfloat16(accB[i2][j2][r] + b3v);
      }
  }
}

// ---------------- per-node metapath attention (bilinear form) ----------------
__global__ __launch_bounds__(64) void k_attn(
    const bf16* __restrict__ p_d, const bf16* __restrict__ pg_d, const float* __restrict__ v2v,
    const float* __restrict__ beta_d, bf16* __restrict__ o_d,
    const bf16* __restrict__ p_z, const bf16* __restrict__ pg_z,
    const float* __restrict__ beta_z, bf16* __restrict__ o_z)
{
  int node = blockIdx.x; int t = threadIdx.x;
  const bf16 *pp, *gg; bf16* outp; const float *betap, *v2p;
  if (node < ND){
    pp = p_d + (long)node*640; gg = pg_d + (long)node*640;
    outp = o_d + (long)node*640; betap = beta_d; v2p = v2v;
  } else {
    int nz = node - ND;
    pp = p_z + (long)nz*640; gg = pg_z + (long)nz*640;
    outp = o_z + (long)nz*640; betap = beta_z; v2p = v2v + 128;
  }
  __shared__ float pl[640], gl[640], v2l[128];
  __shared__ float lg[25], at[25], bv[5];
  const uint* pu = (const uint*)pp;
  const uint* gu = (const uint*)gg;
  for (int i=t; i<320; i+=64){
    uint w = pu[i];
    pl[2*i] = bfl(w); pl[2*i+1] = bfh(w);
    uint g = gu[i];
    gl[2*i] = bfl(g); gl[2*i+1] = bfh(g);
  }
  v2l[t] = v2p[t]; v2l[64+t] = v2p[64+t];
  __syncthreads();
  if (t < 60){
    int pr = t>>1, sub = t&1, h0 = sub*64;
    float s = 0.f;
    if (pr < 25){
      int mi = pr/5, ki = pr - 5*(pr/5);
      for (int h=h0; h<h0+64; h++) s += gl[mi*HID+h]*pl[ki*HID+h];
      s += __shfl_xor(s, 1);
      if (!sub) lg[pr] = s;
    } else {
      int k = pr - 25;
      for (int h=h0; h<h0+64; h++) s += pl[k*HID+h]*v2l[h];
      s += __shfl_xor(s, 1);
      if (!sub) bv[k] = s;
    }
  }
  __syncthreads();
  if (t < 5){
    float l0[5];
    for (int j=0;j<5;j++) l0[j] = lg[t*5+j] + bv[j];
    float mx = l0[0];
    for (int j=1;j<5;j++) mx = fmaxf(mx, l0[j]);
    float e[5], su=0.f;
    for (int j=0;j<5;j++){ e[j] = expf(l0[j]-mx); su += e[j]; }
    for (int j=0;j<5;j++) at[t*5+j] = e[j]/su;
  }
  __syncthreads();
  float bt = betap[0];
  for (int i=t; i<320; i+=64){
    int mm = i>>6, h = (i&63)*2;
    float s0=0.f, s1=0.f;
    #pragma unroll
    for (int k2=0;k2<5;k2++){
      s0 += at[mm*5+k2]*pl[k2*HID+h];
      s1 += at[mm*5+k2]*pl[k2*HID+h+1];
    }
    ((uint*)outp)[i] = packbf2(pl[2*i] + bt*s0, pl[2*i+1] + bt*s1);
  }
}

// ---------------- final GEMM: out(ND,NZ)=A(ND,640)@B(NZ,640)^T ----------------
__global__ __launch_bounds__(256) void k_gemm_final(
    const bf16* __restrict__ Aout, const bf16* __restrict__ Bb, float* __restrict__ out)
{
  __shared__ short As[128*64];
  __shared__ short Bs[128*64];
  int t = threadIdx.x;
  int lane = t&63, wv=t>>6, wr=wv>>1, wc=wv&1;
  int row0 = blockIdx.x*128, col0 = blockIdx.y*128;
  const short* Ag = (const short*)Aout;
  const short* Bg = (const short*)Bb;
  int l15 = lane&15, hi = lane>>4;
  int srow = t>>3;
  int sseg = (t&7) ^ (srow&7);
  f4v acc[4][4] = {};
  for (int kk=0; kk<NCH*HID; kk+=64){
    int mch = kk>>7, h0 = kk&127;
    __syncthreads();
    #pragma unroll
    for (int j=0;j<4;j++){
      int row = j*32 + srow;
      gload16(Ag + ((long)mch*ND + row0+row)*HID + h0 + sseg*8,
              (char*)As + ((j*256 + t)<<4));
      gload16(Bg + (long)(col0+row)*(NCH*HID) + kk + sseg*8,
              (char*)Bs + ((j*256 + t)<<4));
    }
    asm volatile("s_waitcnt vmcnt(0)" ::: "memory");
    __syncthreads();
    #pragma unroll
    for (int sl=0; sl<2; sl++){
      s8v af[4], bg[4];
      #pragma unroll
      for (int i=0;i<4;i++){
        int ra = wr*64 + i*16 + l15;
        af[i] = *(const s8v*)(&As[ra*64 + (((sl*4+hi) ^ (ra&7))*8)]);
        int rb = wc*64 + i*16 + l15;
        bg[i] = *(const s8v*)(&Bs[rb*64 + (((sl*4+hi) ^ (rb&7))*8)]);
      }
      #pragma unroll
      for (int mi=0;mi<4;mi++)
        #pragma unroll
        for (int ni=0;ni<4;ni++)
          acc[mi][ni] = __builtin_amdgcn_mfma_f32_16x16x32_bf16(af[mi], bg[ni], acc[mi][ni],0,0,0);
    }
  }
  #pragma unroll
  for (int mi=0;mi<4;mi++){
    #pragma unroll
    for (int ni=0;ni<4;ni++){
      int col = col0 + wc*64 + ni*16 + l15;
      #pragma unroll
      for (int r=0;r<4;r++){
        int row = row0 + wr*64 + mi*16 + hi*4 + r;
        out[(long)row*NZ + col] = acc[mi][ni][r];
      }
    }
  }
}

extern "C" void kernel_launch(void* const* d_in, const int* in_sizes, int n_in,
                              void* d_out, int out_size, void* d_ws, size_t ws_size,
                              hipStream_t stream)
{
  (void)in_sizes; (void)n_in; (void)out_size;
  const float* feat_d = (const float*)d_in[0];
  const float* feat_z = (const float*)d_in[1];
  const float* att_d  = (const float*)d_in[2];
  const float* att_z  = (const float*)d_in[3];
  const int* src_d = (const int*)d_in[4];
  const int* dst_d = (const int*)d_in[5];
  const int* src_z = (const int*)d_in[6];
  const int* dst_z = (const int*)d_in[7];
  const float* dW1=(const float*)d_in[8];  const float* db1=(const float*)d_in[9];
  const float* dW2=(const float*)d_in[10]; const float* db2=(const float*)d_in[11];
  const float* dW3=(const float*)d_in[12]; const float* db3=(const float*)d_in[13];
  const float* Wq_d=(const float*)d_in[14]; const float* bq_d=(const float*)d_in[15];
  const float* Wk_d=(const float*)d_in[16]; const float* bk_d=(const float*)d_in[17];
  const float* beta_d=(const float*)d_in[18];
  const float* zW1=(const float*)d_in[19]; const float* zb1=(const float*)d_in[20];
  const float* zW2=(const float*)d_in[21]; const float* zb2=(const float*)d_in[22];
  const float* zW3=(const float*)d_in[23]; const float* zb3=(const float*)d_in[24];
  const float* Wq_z=(const float*)d_in[25]; const float* bq_z=(const float*)d_in[26];
  const float* Wk_z=(const float*)d_in[27]; const float* bk_z=(const float*)d_in[28];
  const float* beta_z=(const float*)d_in[29];
  const float* wattn=(const float*)d_in[30];
  const float* Wdec=(const float*)d_in[31]; const float* bdec=(const float*)d_in[32];
  (void)bk_d; (void)bk_z;   // folded out: constant-over-k softmax terms cancel

  char* ws = (char*)d_ws;
  size_t o = 0;
  auto alloc = [&](size_t bytes)->char*{
    size_t r = (o + 255) & ~(size_t)255;
    o = r + bytes;
    return ws + r;
  };
  bf16* featb_d = (bf16*)alloc((size_t)ND*IN_DIM*2);
  bf16* featb_z = (bf16*)alloc((size_t)NZ*IN_DIM*2);
  bf16* Y_d = (bf16*)alloc((size_t)NP*ND*MIDW*2);     // later: pg_z
  bf16* Y_z = (bf16*)alloc((size_t)NP*NZ*MIDW*2);     // later: Bbig
  bf16* h1_d = (bf16*)alloc((size_t)NCH*ND*MIDW*2);   // later: out_d
  bf16* pbuf_d = (bf16*)alloc((size_t)ND*NCH*HID*2);
  bf16* pg_d = (bf16*)alloc((size_t)ND*NCH*HID*2);
  bf16* h1_z = (bf16*)alloc((size_t)NCH*NZ*MIDW*2);   // later: out_z
  bf16* pbuf_z = (bf16*)alloc((size_t)NZ*NCH*HID*2);
  int* csr_d = (int*)alloc((size_t)NP*E_D*4);
  int* csr_z = (int*)alloc((size_t)NP*E_Z*4);
  int* degcur = (int*)alloc((size_t)(NP*ND*2 + NP*NZ*2)*4);
  int* deg_d = degcur;
  int* cur_d = deg_d + NP*ND;
  int* deg_z = cur_d + NP*ND;
  int* cur_z = deg_z + NP*NZ;
  int* off_d = (int*)alloc((size_t)NP*(ND+1)*4);
  int* off_z = (int*)alloc((size_t)NP*(NZ+1)*4);
  bf16* w1t_d = (bf16*)alloc((size_t)NCH*MIDW*IN_DIM*2);
  bf16* w2t_d = (bf16*)alloc((size_t)NCH*MIDW*MIDW*2);
  bf16* w3t_d = (bf16*)alloc((size_t)NCH*HID*MIDW*2);
  bf16* w1t_z = (bf16*)alloc((size_t)NCH*MIDW*IN_DIM*2);
  bf16* w2t_z = (bf16*)alloc((size_t)NCH*MIDW*MIDW*2);
  bf16* w3t_z = (bf16*)alloc((size_t)NCH*HID*MIDW*2);
  bf16* qwb = (bf16*)alloc((size_t)2*HID*HID*2);
  bf16* kwb = (bf16*)alloc((size_t)2*HID*HID*2);
  bf16* Gtb = (bf16*)alloc((size_t)2*HID*HID*2);
  bf16* wdect = (bf16*)alloc((size_t)NCH*HID*HID*2);
  float* v2v = (float*)alloc((size_t)256*4);
  float* wsm = (float*)alloc((size_t)NCH*4);
  bf16* out_d = h1_d;
  bf16* out_z = h1_z;
  bf16* pg_z  = Y_d;     // Y_d dead after agg2; pg_z needs 3.3MB <= 12.6MB
  bf16* Bbig  = Y_z;     // Y_z dead after agg2
  if (ws_size < o) return;

  hipMemsetAsync(degcur, 0, (size_t)(NP*ND*2 + NP*NZ*2)*4, stream);
  k_prep<<<PB10+1, 256, 0, stream>>>(feat_d, feat_z, featb_d, featb_z,
      dW1, dW2, dW3, zW1, zW2, zW3, Wq_d, Wk_d, Wq_z, Wk_z, Wdec,
      w1t_d, w2t_d, w3t_d, w1t_z, w2t_z, w3t_z, qwb, kwb, wdect,
      bq_d, bq_z, v2v, wattn, wsm);
  k_count<<<(NP*E_D + NP*E_Z)/256, 256, 0, stream>>>(src_d, deg_d, src_z, deg_z);
  k_scan<<<2*NP, 256, 0, stream>>>(deg_d, off_d, deg_z, off_z);
  k_scatter<<<(NP*E_D + NP*E_Z)/256, 256, 0, stream>>>(src_d, dst_d, off_d, cur_d, csr_d,
                                                       src_z, dst_z, off_z, cur_z, csr_z);

  // Gt = Wk @ Wq^T (both types) -> (p@G) GEMM operand
  {
    GemmP pg0 = {kwb, qwb, nullptr, Gtb, nullptr, nullptr, 0, (long)HID*HID, HID, (long)HID*HID, HID, HID, HID, 0};
    k_gemm<<<dim3(1, 2, 2), 256, 0, stream>>>(pg0, pg0, 2);
  }
  // A1: channel-0 h1 = relu(feat @ W1_0 + b1_0)
  {
    GemmP pd = {featb_d, w1t_d, db1, h1_d, nullptr, nullptr, 0, 0, MIDW, 0, IN_DIM, MIDW, ND, 1};
    GemmP pz = {featb_z, w1t_z, zb1, h1_z, nullptr, nullptr, 0, 0, MIDW, 0, IN_DIM, MIDW, NZ, 1};
    k_gemm<<<dim3(64, 3, 2), 256, 0, stream>>>(pd, pz, 1);
  }
  // A2: Y_m = att_m * (feat @ W1_{m+1})
  {
    GemmP pd = {featb_d, w1t_d + MIDW*IN_DIM, nullptr, Y_d, nullptr, att_d, ND, 0, MIDW, (long)ND*MIDW, IN_DIM, MIDW, ND, 0};
    GemmP pz = {featb_z, w1t_z + MIDW*IN_DIM, nullptr, Y_z, nullptr, att_z, NZ, 0, MIDW, (long)NZ*MIDW, IN_DIM, MIDW, NZ, 0};
    k_gemm<<<dim3(64, 3, 8), 256, 0, stream>>>(pd, pz, 4);
  }
  // aggregation -> h1 channels 1..4
  k_agg2<<<(NP*ND + NP*NZ)/4, 256, 0, stream>>>(csr_d, off_d, db1, Y_d, h1_d,
                                                csr_z, off_z, zb1, Y_z, h1_z);
  // fused MLP layers 2+3 -> pbuf node-major (n, M, H)
  {
    MlpP pd = {h1_d, w2t_d, db2, w3t_d, db3, pbuf_d, ND};
    MlpP pz = {h1_z, w2t_z, zb2, w3t_z, zb3, pbuf_z, NZ};
    k_mlp23<<<dim3(64, 1, 10), 256, 0, stream>>>(pd, pz, 5);
  }
  // pg = p @ G (per type)
  {
    GemmP pd = {pbuf_d, Gtb, nullptr, pg_d, nullptr, nullptr, 0, 0, HID, 0, HID, HID, ND*NCH, 0};
    GemmP pz = {pbuf_z, Gtb + HID*HID, nullptr, pg_z, nullptr, nullptr, 0, 0, HID, 0, HID, HID, NZ*NCH, 0};
    k_gemm<<<dim3(320, 2, 2), 256, 0, stream>>>(pd, pz, 1);
  }
  // metapath attention
  k_attn<<<ND + NZ, 64, 0, stream>>>(pbuf_d, pg_d, v2v, beta_d, out_d,
                                     pbuf_z, pg_z, beta_z, out_z);
  // decoder: Bbig[z, m*128+h] = w_m * (out_z_view[m] @ Wdec[m] + bdec[m])
  {
    GemmP pz = {out_z, wdect, bdec, Bbig, wsm, nullptr, 0, (long)NZ*HID, (long)NCH*HID, HID, HID, HID, NZ, 0};
    k_gemm<<<dim3(32, 2, 5), 256, 0, stream>>>(pz, pz, 5);
  }
  // final
  k_gemm_final<<<dim3(64, 32), 256, 0, stream>>>(out_d, Bbig, (float*)d_out);
}

// Round 6
// 291.112 us; speedup vs baseline: 2.1199x; 1.3726x over previous
//
#include <hip/hip_runtime.h>
#include <hip/hip_bf16.h>

#define ND 8192
#define NZ 4096
#define IN_DIM 256
#define HID 128
#define MIDW 192
#define NP 4
#define NCH 5
#define DEG 32
#define E_D (ND*DEG)
#define E_Z (NZ*DEG)
#define CAP 96          // fixed-capacity edge-list slots per (metapath, src)

typedef __hip_bfloat16 bf16;
typedef __attribute__((ext_vector_type(8))) short s8v;
typedef __attribute__((ext_vector_type(4))) float f4v;

static __device__ __forceinline__ unsigned short f2bf(float x){
  bf16 b = __float2bfloat16(x);
  return *reinterpret_cast<unsigned short*>(&b);
}
static __device__ __forceinline__ uint packbf2(float a, float b){
  return (uint)f2bf(a) | ((uint)f2bf(b) << 16);
}
static __device__ __forceinline__ float bfl(uint w){ return __uint_as_float(w<<16); }
static __device__ __forceinline__ float bfh(uint w){ return __uint_as_float(w & 0xffff0000u); }
static __device__ __forceinline__ void gload16(const void* g, void* l){
  __builtin_amdgcn_global_load_lds(
      (const __attribute__((address_space(1))) unsigned int*)g,
      (__attribute__((address_space(3))) unsigned int*)l, 16, 0, 0);
}

// ---------------- mega prep: edge scatter + cvts + transposes + G + v2 ----------------
static __device__ __forceinline__ void tpz(const float* __restrict__ in, bf16* __restrict__ out,
                                           int rows, int cols, long idx){
  int per = rows*cols;
  int b = (int)(idx / per);
  int rem = (int)(idx - (long)b*per);
  int r = rem / cols, c = rem - r*cols;
  out[(long)b*per + (long)c*rows + r] = __float2bfloat16(in[idx]);
}

#define B_SD 0
#define B_SZ 4096
#define B_CD 6144
#define B_CZ 8192
#define B_W1D 9216
#define B_W1Z 10176
#define B_W2D 11136
#define B_W2Z 11856
#define B_W3D 12576
#define B_W3Z 13056
#define B_WDEC 13536
#define B_G 13856
#define B_V 13984
#define B_END 13985

__global__ __launch_bounds__(256) void k_prep(
    const int* __restrict__ src_d, const int* __restrict__ dst_d,
    const int* __restrict__ src_z, const int* __restrict__ dst_z,
    int* __restrict__ cur_d, int* __restrict__ cur_z,
    int* __restrict__ edl_d, int* __restrict__ edl_z,
    const float* feat_d, const float* feat_z, bf16* featb_d, bf16* featb_z,
    const float* dW1, const float* dW2, const float* dW3,
    const float* zW1, const float* zW2, const float* zW3,
    bf16* w1t_d, bf16* w2t_d, bf16* w3t_d, bf16* w1t_z, bf16* w2t_z, bf16* w3t_z,
    const float* Wdec, bf16* wdect,
    const float* Wq_d, const float* Wk_d, const float* Wq_z, const float* Wk_z,
    bf16* Gtb,
    const float* bq_d, const float* bq_z, float* v2v,
    const float* wattn, float* wsm)
{
  int b = blockIdx.x, t = threadIdx.x;
  if (b < B_SZ){
    long i = (long)b*256 + t;              // 0 .. NP*E_D
    int m = (int)(i >> 18);                // E_D = 2^18
    int s = src_d[i];
    int pos = atomicAdd(&cur_d[(m<<13) + s], 1);
    if (pos < CAP) edl_d[((long)((m<<13) + s))*CAP + pos] = dst_d[i];
  } else if (b < B_CD){
    long j = (long)(b - B_SZ)*256 + t;     // 0 .. NP*E_Z
    int m = (int)(j >> 17);                // E_Z = 2^17
    int s = src_z[j];
    int pos = atomicAdd(&cur_z[(m<<12) + s], 1);
    if (pos < CAP) edl_z[((long)((m<<12) + s))*CAP + pos] = dst_z[j];
  } else if (b < B_CZ){
    long i4 = (long)(b - B_CD)*256 + t;
    float4 v = ((const float4*)feat_d)[i4];
    ushort4 o; o.x=f2bf(v.x); o.y=f2bf(v.y); o.z=f2bf(v.z); o.w=f2bf(v.w);
    ((ushort4*)featb_d)[i4] = o;
  } else if (b < B_W1D){
    long i4 = (long)(b - B_CZ)*256 + t;
    float4 v = ((const float4*)feat_z)[i4];
    ushort4 o; o.x=f2bf(v.x); o.y=f2bf(v.y); o.z=f2bf(v.z); o.w=f2bf(v.w);
    ((ushort4*)featb_z)[i4] = o;
  } else if (b < B_W1Z){ tpz(dW1, w1t_d, IN_DIM, MIDW, (long)(b-B_W1D)*256 + t); }
  else if (b < B_W2D){ tpz(zW1, w1t_z, IN_DIM, MIDW, (long)(b-B_W1Z)*256 + t); }
  else if (b < B_W2Z){ tpz(dW2, w2t_d, MIDW, MIDW, (long)(b-B_W2D)*256 + t); }
  else if (b < B_W3D){ tpz(zW2, w2t_z, MIDW, MIDW, (long)(b-B_W2Z)*256 + t); }
  else if (b < B_W3Z){ tpz(dW3, w3t_d, MIDW, HID, (long)(b-B_W3D)*256 + t); }
  else if (b < B_WDEC){ tpz(zW3, w3t_z, MIDW, HID, (long)(b-B_W3Z)*256 + t); }
  else if (b < B_G){ tpz(Wdec, wdect, HID, HID, (long)(b-B_WDEC)*256 + t); }
  else if (b < B_V){
    // Gt[c,h'] = sum_j Wq[h',j]*Wk[c,j]   (BT operand for pg = p @ (Wq Wk^T))
    int cc = (b - B_G)*2 + (t>>7);         // 0..255 : d rows then z rows
    int hp = t & 127;
    const float* Wq = cc < 128 ? Wq_d : Wq_z;
    const float* Wk = cc < 128 ? Wk_d : Wk_z;
    int c = cc & 127;
    float s = 0.f;
    for (int j=0;j<HID;j++) s += Wq[hp*HID+j]*Wk[c*HID+j];
    Gtb[(cc < 128 ? 0 : HID*HID) + c*HID + hp] = __float2bfloat16(s);
  } else {
    // v2[i] = sum_j Wk[i,j]*bq[j]
    if (t < 128){
      float s = 0.f;
      for (int j=0;j<HID;j++) s += Wk_d[t*HID+j]*bq_d[j];
      v2v[t] = s;
    } else {
      int tt = t-128;
      float s = 0.f;
      for (int j=0;j<HID;j++) s += Wk_z[tt*HID+j]*bq_z[j];
      v2v[128+tt] = s;
    }
    if (t == 0){
      float mx = wattn[0];
      for (int i=1;i<NCH;i++) mx = fmaxf(mx, wattn[i]);
      float e[NCH], s=0.f;
      for (int i=0;i<NCH;i++){ e[i]=expf(wattn[i]-mx); s+=e[i]; }
      for (int i=0;i<NCH;i++) wsm[i]=e[i]/s;
    }
  }
}

// ---------------- stage 1: A1 (ch0 h1) + A2 (Y channels) merged, z=0..9 ----------------
__global__ __launch_bounds__(256) void k_stage1(
    const bf16* __restrict__ featb_d, const bf16* __restrict__ featb_z,
    const bf16* __restrict__ w1t_d, const bf16* __restrict__ w1t_z,
    const float* __restrict__ db1, const float* __restrict__ zb1,
    const float* __restrict__ att_d, const float* __restrict__ att_z,
    bf16* __restrict__ h1_d, bf16* __restrict__ h1_z,
    bf16* __restrict__ Y_d, bf16* __restrict__ Y_z)
{
  int z = blockIdx.z, typ = z/5, c = z - 5*(z/5);
  int n = typ ? NZ : ND;
  long row0 = (long)blockIdx.x*128;
  if (row0 >= n) return;
  int col0 = blockIdx.y*64;
  __shared__ short As[128*40];
  __shared__ short Bs[64*40];
  int t = threadIdx.x, lane = t&63, wv = t>>6;
  int l15 = lane&15, kof = (lane>>4)*8;
  const short* Ag = (const short*)(typ ? featb_z : featb_d);
  const short* Bg = (const short*)(typ ? w1t_z : w1t_d) + (long)c*MIDW*IN_DIM;
  f4v acc[2][4] = {};
  for (int kk=0; kk<IN_DIM; kk+=32){
    __syncthreads();
    #pragma unroll
    for (int j=0;j<2;j++){
      int c2 = t + j*256;
      int row = c2>>2, sub = c2&3;
      *(s8v*)(&As[row*40 + sub*8]) = *(const s8v*)(Ag + (row0+row)*IN_DIM + kk + sub*8);
    }
    { int row = t>>2, sub = t&3;
      *(s8v*)(&Bs[row*40 + sub*8]) = *(const s8v*)(Bg + (long)(col0+row)*IN_DIM + kk + sub*8); }
    __syncthreads();
    s8v af[2], bfr[4];
    #pragma unroll
    for (int i2=0;i2<2;i2++) af[i2] = *(const s8v*)(&As[(wv*32 + i2*16 + l15)*40 + kof]);
    #pragma unroll
    for (int j2=0;j2<4;j2++) bfr[j2] = *(const s8v*)(&Bs[(j2*16 + l15)*40 + kof]);
    #pragma unroll
    for (int i2=0;i2<2;i2++)
      #pragma unroll
      for (int j2=0;j2<4;j2++)
        acc[i2][j2] = __builtin_amdgcn_mfma_f32_16x16x32_bf16(af[i2], bfr[j2], acc[i2][j2],0,0,0);
  }
  if (c == 0){
    const float* bb = typ ? zb1 : db1;
    bf16* outp = typ ? h1_z : h1_d;
    #pragma unroll
    for (int i2=0;i2<2;i2++)
      #pragma unroll
      for (int j2=0;j2<4;j2++){
        int col = col0 + j2*16 + l15;
        float bv = bb[col];
        #pragma unroll
        for (int r=0;r<4;r++){
          long row = row0 + wv*32 + i2*16 + (lane>>4)*4 + r;
          outp[row*MIDW + col] = __float2bfloat16(fmaxf(acc[i2][j2][r] + bv, 0.f));
        }
      }
  } else {
    const float* rs = (typ ? att_z : att_d) + (long)(c-1)*n;
    bf16* outp = (typ ? Y_z : Y_d) + (long)(c-1)*n*MIDW;
    #pragma unroll
    for (int i2=0;i2<2;i2++)
      #pragma unroll
      for (int j2=0;j2<4;j2++){
        int col = col0 + j2*16 + l15;
        #pragma unroll
        for (int r=0;r<4;r++){
          long row = row0 + wv*32 + i2*16 + (lane>>4)*4 + r;
          outp[row*MIDW + col] = __float2bfloat16(acc[i2][j2][r] * rs[row]);
        }
      }
  }
}

// ---------------- aggregation (fixed-cap edge lists, shfl-broadcast) ----------------
__global__ __launch_bounds__(256) void k_agg2(
    const int* __restrict__ edl_d, const int* __restrict__ cur_d, const float* __restrict__ bias_d,
    const bf16* __restrict__ Y_d, bf16* __restrict__ h1_d,
    const int* __restrict__ edl_z, const int* __restrict__ cur_z, const float* __restrict__ bias_z,
    const bf16* __restrict__ Y_z, bf16* __restrict__ h1_z)
{
  int wid = (blockIdx.x*256 + threadIdx.x) >> 6;
  int lane = threadIdx.x & 63;
  const int *edl, *cur; const float* bias; const uint* Yb; bf16* h1; int n, m;
  if (wid < NP*ND){
    m = wid >> 13; int s0 = wid & (ND-1);
    edl = edl_d; cur = cur_d; bias = bias_d; h1 = h1_d; n = ND;
    Yb = (const uint*)Y_d + (long)m*ND*96;
    wid = s0;
  } else {
    int w2 = wid - NP*ND;
    m = w2 >> 12; int s0 = w2 & (NZ-1);
    edl = edl_z; cur = cur_z; bias = bias_z; h1 = h1_z; n = NZ;
    Yb = (const uint*)Y_z + (long)m*NZ*96;
    wid = s0;
  }
  int s = wid;
  int cnt0 = cur[(long)m*n + s];
  int cnt = cnt0 < CAP ? cnt0 : CAP;
  const int* lp = edl + ((long)m*n + s)*CAP;
  bool hi2 = lane < 32;
  float a0=0.f,a1=0.f,a2=0.f,a3=0.f;
  for (int base=0; base<cnt; base+=64){
    int rem = cnt - base;
    int idx = (lane < rem) ? lane : (rem-1);
    int e = lp[base + idx];
    int lim = rem < 64 ? rem : 64;
    int j = 0;
    for (; j+1<lim; j+=2){
      int d0 = __shfl(e, j), d1 = __shfl(e, j+1);
      const uint* r0 = Yb + (long)d0*96;
      const uint* r1 = Yb + (long)d1*96;
      uint w0 = r0[lane], w1 = r1[lane];
      uint v0 = hi2 ? r0[64+lane] : 0u;
      uint v1 = hi2 ? r1[64+lane] : 0u;
      a0 += bfl(w0)+bfl(w1); a1 += bfh(w0)+bfh(w1);
      a2 += bfl(v0)+bfl(v1); a3 += bfh(v0)+bfh(v1);
    }
    if (j < lim){
      int d0 = __shfl(e, j);
      const uint* r0 = Yb + (long)d0*96;
      uint w0 = r0[lane];
      uint v0 = hi2 ? r0[64+lane] : 0u;
      a0 += bfl(w0); a1 += bfh(w0);
      a2 += bfl(v0); a3 += bfh(v0);
    }
  }
  float inv = 1.0f / fmaxf((float)cnt0, 1.0f);
  const float* bb = bias + (m+1)*MIDW;
  float2 b0 = *(const float2*)(bb + 2*lane);
  uint* hrow = (uint*)((short*)h1 + ((long)(m+1)*n + s)*MIDW);
  hrow[lane] = packbf2(fmaxf(a0*inv + b0.x, 0.f), fmaxf(a1*inv + b0.y, 0.f));
  if (hi2){
    float2 b1v = *(const float2*)(bb + 128 + 2*lane);
    hrow[64+lane] = packbf2(fmaxf(a2*inv + b1v.x, 0.f), fmaxf(a3*inv + b1v.y, 0.f));
  }
}

// ---------------- generic batched GEMM (decoder only now) ----------------
struct GemmP {
  const bf16* A; const bf16* BT; const float* bias; bf16* out;
  const float* scale; const float* rowsc;
  long rs_moff, a_moff, out_rstride, out_moff;
  int K, N, nrows, relu;
};

__global__ __launch_bounds__(256) void k_gemm(GemmP P0, GemmP P1, int zsplit)
{
  const GemmP& p = ((int)blockIdx.z < zsplit) ? P0 : P1;
  int m = ((int)blockIdx.z < zsplit) ? blockIdx.z : blockIdx.z - zsplit;
  long row0 = (long)blockIdx.x*128;
  if (row0 >= p.nrows) return;
  int col0 = blockIdx.y*64;
  if (col0 >= p.N) return;
  __shared__ short As[128*40];
  __shared__ short Bs[64*40];
  int t = threadIdx.x;
  const short* Ag = (const short*)p.A + m*p.a_moff;
  const short* Bg = (const short*)p.BT + (long)m*p.N*p.K;
  int lane = t&63, wv = t>>6;
  int l15 = lane&15, kof = (lane>>4)*8;
  int K = p.K;
  f4v acc[2][4] = {};
  for (int kk=0; kk<K; kk+=32){
    __syncthreads();
    #pragma unroll
    for (int j=0;j<2;j++){
      int c = t + j*256;
      int row = c>>2, sub = c&3;
      *(s8v*)(&As[row*40 + sub*8]) = *(const s8v*)(Ag + (row0+row)*K + kk + sub*8);
    }
    { int row = t>>2, sub = t&3;
      *(s8v*)(&Bs[row*40 + sub*8]) = *(const s8v*)(Bg + (long)(col0+row)*K + kk + sub*8); }
    __syncthreads();
    s8v af[2], bfr[4];
    #pragma unroll
    for (int i2=0;i2<2;i2++) af[i2] = *(const s8v*)(&As[(wv*32 + i2*16 + l15)*40 + kof]);
    #pragma unroll
    for (int j2=0;j2<4;j2++) bfr[j2] = *(const s8v*)(&Bs[(j2*16 + l15)*40 + kof]);
    #pragma unroll
    for (int i2=0;i2<2;i2++)
      #pragma unroll
      for (int j2=0;j2<4;j2++)
        acc[i2][j2] = __builtin_amdgcn_mfma_f32_16x16x32_bf16(af[i2], bfr[j2], acc[i2][j2],0,0,0);
  }
  float sc = p.scale ? p.scale[m] : 1.0f;
  #pragma unroll
  for (int i2=0;i2<2;i2++){
    #pragma unroll
    for (int j2=0;j2<4;j2++){
      int col = col0 + j2*16 + l15;
      float bv = p.bias ? p.bias[m*p.N + col] : 0.f;
      #pragma unroll
      for (int r=0;r<4;r++){
        long row = row0 + wv*32 + i2*16 + (lane>>4)*4 + r;
        float v = acc[i2][j2][r] + bv;
        if (p.relu) v = fmaxf(v, 0.f);
        v *= sc;
        if (p.rowsc) v *= p.rowsc[m*p.rs_moff + row];
        p.out[m*p.out_moff + row*p.out_rstride + col] = __float2bfloat16(v);
      }
    }
  }
}

// ---------------- fused MLP 2+3 + pg phase: p = relu(h1@W2+b2)@W3+b3 ; pg = p@G ----------------
struct MlpP { const bf16* h1; const bf16* w2t; const float* b2;
              const bf16* w3t; const float* b3; bf16* pout; bf16* pgout;
              const bf16* gt; int n; };

__global__ __launch_bounds__(256) void k_mlp23(MlpP P0, MlpP P1, int zsplit)
{
  const MlpP& p = ((int)blockIdx.z < zsplit) ? P0 : P1;
  int m = ((int)blockIdx.z < zsplit) ? blockIdx.z : blockIdx.z - zsplit;
  int row0 = blockIdx.x*128;
  if (row0 >= p.n) return;
  __shared__ short h2s[128*200];
  __shared__ short As[128*40];
  __shared__ short Bs[192*40];
  int t = threadIdx.x, lane = t&63, wv = t>>6;
  int l15 = lane&15, hi = lane>>4, kof = hi*8;
  const short* Ag = (const short*)p.h1 + ((long)m*p.n + row0)*MIDW;
  const short* Bg = (const short*)p.w2t + (long)m*MIDW*MIDW;
  f4v accA[2][12] = {};
  for (int kk=0; kk<MIDW; kk+=32){
    __syncthreads();
    #pragma unroll
    for (int j=0;j<2;j++){
      int c = t + j*256;
      int row = c>>2, sub = c&3;
      *(s8v*)(&As[row*40 + sub*8]) = *(const s8v*)(Ag + (long)row*MIDW + kk + sub*8);
    }
    #pragma unroll
    for (int j=0;j<3;j++){
      int c = t + j*256;
      int row = c>>2, sub = c&3;
      *(s8v*)(&Bs[row*40 + sub*8]) = *(const s8v*)(Bg + (long)row*MIDW + kk + sub*8);
    }
    __syncthreads();
    s8v af[2], bfr[12];
    #pragma unroll
    for (int i2=0;i2<2;i2++) af[i2] = *(const s8v*)(&As[(wv*32 + i2*16 + l15)*40 + kof]);
    #pragma unroll
    for (int j2=0;j2<12;j2++) bfr[j2] = *(const s8v*)(&Bs[(j2*16 + l15)*40 + kof]);
    #pragma unroll
    for (int i2=0;i2<2;i2++)
      #pragma unroll
      for (int j2=0;j2<12;j2++)
        accA[i2][j2] = __builtin_amdgcn_mfma_f32_16x16x32_bf16(af[i2], bfr[j2], accA[i2][j2],0,0,0);
  }
  // h2 = relu(accA + b2) -> h2s
  float b2l[12];
  #pragma unroll
  for (int j2=0;j2<12;j2++) b2l[j2] = p.b2[m*MIDW + j2*16 + l15];
  #pragma unroll
  for (int i2=0;i2<2;i2++)
    #pragma unroll
    for (int j2=0;j2<12;j2++)
      #pragma unroll
      for (int r=0;r<4;r++){
        int rl = wv*32 + i2*16 + hi*4 + r;
        h2s[rl*200 + j2*16 + l15] = (short)f2bf(fmaxf(accA[i2][j2][r] + b2l[j2], 0.f));
      }
  // phase B: p = h2 @ w3t^T + b3
  const short* Cg = (const short*)p.w3t + (long)m*HID*MIDW;
  f4v accB[2][8] = {};
  for (int kk=0; kk<MIDW; kk+=32){
    __syncthreads();
    #pragma unroll
    for (int j=0;j<2;j++){
      int c = t + j*256;
      int row = c>>2, sub = c&3;
      *(s8v*)(&Bs[row*40 + sub*8]) = *(const s8v*)(Cg + (long)row*MIDW + kk + sub*8);
    }
    __syncthreads();
    s8v af[2], bfr[8];
    #pragma unroll
    for (int i2=0;i2<2;i2++) af[i2] = *(const s8v*)(&h2s[(wv*32 + i2*16 + l15)*200 + kk + kof]);
    #pragma unroll
    for (int j2=0;j2<8;j2++) bfr[j2] = *(const s8v*)(&Bs[(j2*16 + l15)*40 + kof]);
    #pragma unroll
    for (int i2=0;i2<2;i2++)
      #pragma unroll
      for (int j2=0;j2<8;j2++)
        accB[i2][j2] = __builtin_amdgcn_mfma_f32_16x16x32_bf16(af[i2], bfr[j2], accB[i2][j2],0,0,0);
  }
  __syncthreads();              // all phase-B h2s reads done before p overwrites it
  // p -> pbuf (global) and h2s cols 0..127 (for phase C)
  #pragma unroll
  for (int j2=0;j2<8;j2++){
    float b3v = p.b3[m*HID + j2*16 + l15];
    #pragma unroll
    for (int i2=0;i2<2;i2++)
      #pragma unroll
      for (int r=0;r<4;r++){
        int rl = wv*32 + i2*16 + hi*4 + r;
        unsigned short hv = f2bf(accB[i2][j2][r] + b3v);
        p.pout[((long)(row0+rl))*(NCH*HID) + m*HID + j2*16 + l15] = *(bf16*)&hv;
        h2s[rl*200 + j2*16 + l15] = (short)hv;
      }
  }
  // phase C: pg = p @ Gt^T
  const short* Gg = (const short*)p.gt;
  f4v accC[2][8] = {};
  for (int kk=0; kk<HID; kk+=32){
    __syncthreads();
    #pragma unroll
    for (int j=0;j<2;j++){
      int c = t + j*256;
      int row = c>>2, sub = c&3;
      *(s8v*)(&Bs[row*40 + sub*8]) = *(const s8v*)(Gg + (long)row*HID + kk + sub*8);
    }
    __syncthreads();
    s8v af[2], bfr[8];
    #pragma unroll
    for (int i2=0;i2<2;i2++) af[i2] = *(const s8v*)(&h2s[(wv*32 + i2*16 + l15)*200 + kk + kof]);
    #pragma unroll
    for (int j2=0;j2<8;j2++) bfr[j2] = *(const s8v*)(&Bs[(j2*16 + l15)*40 + kof]);
    #pragma unroll
    for (int i2=0;i2<2;i2++)
      #pragma unroll
      for (int j2=0;j2<8;j2++)
        accC[i2][j2] = __builtin_amdgcn_mfma_f32_16x16x32_bf16(af[i2], bfr[j2], accC[i2][j2],0,0,0);
  }
  #pragma unroll
  for (int j2=0;j2<8;j2++)
    #pragma unroll
    for (int i2=0;i2<2;i2++)
      #pragma unroll
      for (int r=0;r<4;r++){
        long row = row0 + wv*32 + i2*16 + hi*4 + r;
        p.pgout[row*(NCH*HID) + m*HID + j2*16 + l15] = __float2bfloat16(accC[i2][j2][r]);
      }
}

// ---------------- per-node metapath attention (bilinear) ----------------
__global__ __launch_bounds__(64) void k_attn(
    const bf16* __restrict__ p_d, const bf16* __restrict__ pg_d, const float* __restrict__ v2v,
    const float* __restrict__ beta_d, bf16* __restrict__ o_d,
    const bf16* __restrict__ p_z, const bf16* __restrict__ pg_z,
    const float* __restrict__ beta_z, bf16* __restrict__ o_z)
{
  int node = blockIdx.x; int t = threadIdx.x;
  const bf16 *pp, *gg; bf16* outp; const float *betap, *v2p;
  if (node < ND){
    pp = p_d + (long)node*640; gg = pg_d + (long)node*640;
    outp = o_d + (long)node*640; betap = beta_d; v2p = v2v;
  } else {
    int nz = node - ND;
    pp = p_z + (long)nz*640; gg = pg_z + (long)nz*640;
    outp = o_z + (long)nz*640; betap = beta_z; v2p = v2v + 128;
  }
  __shared__ float pl[640], gl[640], v2l[128];
  __shared__ float lg[25], at[25], bv[5];
  const uint* pu = (const uint*)pp;
  const uint* gu = (const uint*)gg;
  for (int i=t; i<320; i+=64){
    uint w = pu[i];
    pl[2*i] = bfl(w); pl[2*i+1] = bfh(w);
    uint g = gu[i];
    gl[2*i] = bfl(g); gl[2*i+1] = bfh(g);
  }
  v2l[t] = v2p[t]; v2l[64+t] = v2p[64+t];
  __syncthreads();
  if (t < 60){
    int pr = t>>1, sub = t&1, h0 = sub*64;
    float s = 0.f;
    if (pr < 25){
      int mi = pr/5, ki = pr - 5*(pr/5);
      for (int h=h0; h<h0+64; h++) s += gl[mi*HID+h]*pl[ki*HID+h];
      s += __shfl_xor(s, 1);
      if (!sub) lg[pr] = s;
    } else {
      int k = pr - 25;
      for (int h=h0; h<h0+64; h++) s += pl[k*HID+h]*v2l[h];
      s += __shfl_xor(s, 1);
      if (!sub) bv[k] = s;
    }
  }
  __syncthreads();
  if (t < 5){
    float l0[5];
    for (int j=0;j<5;j++) l0[j] = lg[t*5+j] + bv[j];
    float mx = l0[0];
    for (int j=1;j<5;j++) mx = fmaxf(mx, l0[j]);
    float e[5], su=0.f;
    for (int j=0;j<5;j++){ e[j] = expf(l0[j]-mx); su += e[j]; }
    for (int j=0;j<5;j++) at[t*5+j] = e[j]/su;
  }
  __syncthreads();
  float bt = betap[0];
  for (int i=t; i<320; i+=64){
    int mm = i>>6, h = (i&63)*2;
    float s0=0.f, s1=0.f;
    #pragma unroll
    for (int k2=0;k2<5;k2++){
      s0 += at[mm*5+k2]*pl[k2*HID+h];
      s1 += at[mm*5+k2]*pl[k2*HID+h+1];
    }
    ((uint*)outp)[i] = packbf2(pl[2*i] + bt*s0, pl[2*i+1] + bt*s1);
  }
}

// ---------------- final GEMM: out(ND,NZ)=A(ND,640)@B(NZ,640)^T ----------------
__global__ __launch_bounds__(256) void k_gemm_final(
    const bf16* __restrict__ Aout, const bf16* __restrict__ Bb, float* __restrict__ out)
{
  __shared__ short As[128*64];
  __shared__ short Bs[128*64];
  int t = threadIdx.x;
  int lane = t&63, wv=t>>6, wr=wv>>1, wc=wv&1;
  int row0 = blockIdx.x*128, col0 = blockIdx.y*128;
  const short* Ag = (const short*)Aout;
  const short* Bg = (const short*)Bb;
  int l15 = lane&15, hi = lane>>4;
  int srow = t>>3;
  int sseg = (t&7) ^ (srow&7);
  f4v acc[4][4] = {};
  for (int kk=0; kk<NCH*HID; kk+=64){
    int mch = kk>>7, h0 = kk&127;
    __syncthreads();
    #pragma unroll
    for (int j=0;j<4;j++){
      int row = j*32 + srow;
      gload16(Ag + ((long)mch*ND + row0+row)*HID + h0 + sseg*8,
              (char*)As + ((j*256 + t)<<4));
      gload16(Bg + (long)(col0+row)*(NCH*HID) + kk + sseg*8,
              (char*)Bs + ((j*256 + t)<<4));
    }
    asm volatile("s_waitcnt vmcnt(0)" ::: "memory");
    __syncthreads();
    #pragma unroll
    for (int sl=0; sl<2; sl++){
      s8v af[4], bg[4];
      #pragma unroll
      for (int i=0;i<4;i++){
        int ra = wr*64 + i*16 + l15;
        af[i] = *(const s8v*)(&As[ra*64 + (((sl*4+hi) ^ (ra&7))*8)]);
        int rb = wc*64 + i*16 + l15;
        bg[i] = *(const s8v*)(&Bs[rb*64 + (((sl*4+hi) ^ (rb&7))*8)]);
      }
      #pragma unroll
      for (int mi=0;mi<4;mi++)
        #pragma unroll
        for (int ni=0;ni<4;ni++)
          acc[mi][ni] = __builtin_amdgcn_mfma_f32_16x16x32_bf16(af[mi], bg[ni], acc[mi][ni],0,0,0);
    }
  }
  #pragma unroll
  for (int mi=0;mi<4;mi++){
    #pragma unroll
    for (int ni=0;ni<4;ni++){
      int col = col0 + wc*64 + ni*16 + l15;
      #pragma unroll
      for (int r=0;r<4;r++){
        int row = row0 + wr*64 + mi*16 + hi*4 + r;
        out[(long)row*NZ + col] = acc[mi][ni][r];
      }
    }
  }
}

extern "C" void kernel_launch(void* const* d_in, const int* in_sizes, int n_in,
                              void* d_out, int out_size, void* d_ws, size_t ws_size,
                              hipStream_t stream)
{
  (void)in_sizes; (void)n_in; (void)out_size;
  const float* feat_d = (const float*)d_in[0];
  const float* feat_z = (const float*)d_in[1];
  const float* att_d  = (const float*)d_in[2];
  const float* att_z  = (const float*)d_in[3];
  const int* src_d = (const int*)d_in[4];
  const int* dst_d = (const int*)d_in[5];
  const int* src_z = (const int*)d_in[6];
  const int* dst_z = (const int*)d_in[7];
  const float* dW1=(const float*)d_in[8];  const float* db1=(const float*)d_in[9];
  const float* dW2=(const float*)d_in[10]; const float* db2=(const float*)d_in[11];
  const float* dW3=(const float*)d_in[12]; const float* db3=(const float*)d_in[13];
  const float* Wq_d=(const float*)d_in[14]; const float* bq_d=(const float*)d_in[15];
  const float* Wk_d=(const float*)d_in[16]; const float* bk_d=(const float*)d_in[17];
  const float* beta_d=(const float*)d_in[18];
  const float* zW1=(const float*)d_in[19]; const float* zb1=(const float*)d_in[20];
  const float* zW2=(const float*)d_in[21]; const float* zb2=(const float*)d_in[22];
  const float* zW3=(const float*)d_in[23]; const float* zb3=(const float*)d_in[24];
  const float* Wq_z=(const float*)d_in[25]; const float* bq_z=(const float*)d_in[26];
  const float* Wk_z=(const float*)d_in[27]; const float* bk_z=(const float*)d_in[28];
  const float* beta_z=(const float*)d_in[29];
  const float* wattn=(const float*)d_in[30];
  const float* Wdec=(const float*)d_in[31]; const float* bdec=(const float*)d_in[32];
  (void)bk_d; (void)bk_z;   // constant-over-k softmax terms cancel

  char* ws = (char*)d_ws;
  size_t o = 0;
  auto alloc = [&](size_t bytes)->char*{
    size_t r = (o + 255) & ~(size_t)255;
    o = r + bytes;
    return ws + r;
  };
  bf16* featb_d = (bf16*)alloc((size_t)ND*IN_DIM*2);
  bf16* featb_z = (bf16*)alloc((size_t)NZ*IN_DIM*2);
  bf16* Y_d = (bf16*)alloc((size_t)NP*ND*MIDW*2);       // later: pg_z
  bf16* Y_z = (bf16*)alloc((size_t)NP*NZ*MIDW*2);       // later: Bbig
  bf16* h1_d = (bf16*)alloc((size_t)NCH*ND*MIDW*2);     // later: out_d
  bf16* h1_z = (bf16*)alloc((size_t)NCH*NZ*MIDW*2);     // later: out_z
  bf16* pbuf_d = (bf16*)alloc((size_t)ND*NCH*HID*2);
  int* edl_d = (int*)alloc((size_t)NP*ND*CAP*4);        // later: pg_d
  int* edl_z = (int*)alloc((size_t)NP*NZ*CAP*4);        // later: pbuf_z
  int* cur = (int*)alloc((size_t)(NP*ND + NP*NZ)*4);
  int* cur_d = cur;
  int* cur_z = cur + NP*ND;
  bf16* w1t_d = (bf16*)alloc((size_t)NCH*MIDW*IN_DIM*2);
  bf16* w2t_d = (bf16*)alloc((size_t)NCH*MIDW*MIDW*2);
  bf16* w3t_d = (bf16*)alloc((size_t)NCH*HID*MIDW*2);
  bf16* w1t_z = (bf16*)alloc((size_t)NCH*MIDW*IN_DIM*2);
  bf16* w2t_z = (bf16*)alloc((size_t)NCH*MIDW*MIDW*2);
  bf16* w3t_z = (bf16*)alloc((size_t)NCH*HID*MIDW*2);
  bf16* Gtb = (bf16*)alloc((size_t)2*HID*HID*2);
  bf16* wdect = (bf16*)alloc((size_t)NCH*HID*HID*2);
  float* v2v = (float*)alloc((size_t)256*4);
  float* wsm = (float*)alloc((size_t)NCH*4);
  bf16* out_d = h1_d;
  bf16* out_z = h1_z;
  bf16* pg_z  = Y_d;            // Y_d dead after agg2 (5.2MB <= 12.6MB)
  bf16* Bbig  = Y_z;            // Y_z dead after agg2
  bf16* pg_d  = (bf16*)edl_d;   // edl dead after agg2 (10.5MB <= 12.6MB)
  bf16* pbuf_z = (bf16*)edl_z;  // (5.2MB <= 6.3MB)
  if (ws_size < o) return;

  hipMemsetAsync(cur, 0, (size_t)(NP*ND + NP*NZ)*4, stream);
  k_prep<<<B_END, 256, 0, stream>>>(src_d, dst_d, src_z, dst_z, cur_d, cur_z, edl_d, edl_z,
      feat_d, feat_z, featb_d, featb_z,
      dW1, dW2, dW3, zW1, zW2, zW3,
      w1t_d, w2t_d, w3t_d, w1t_z, w2t_z, w3t_z,
      Wdec, wdect, Wq_d, Wk_d, Wq_z, Wk_z, Gtb,
      bq_d, bq_z, v2v, wattn, wsm);
  // stage 1: A1 + A2 merged (10 sub-problems)
  k_stage1<<<dim3(64, 3, 10), 256, 0, stream>>>(featb_d, featb_z, w1t_d, w1t_z,
      db1, zb1, att_d, att_z, h1_d, h1_z, Y_d, Y_z);
  // aggregation -> h1 channels 1..4
  k_agg2<<<(NP*ND + NP*NZ)/4, 256, 0, stream>>>(edl_d, cur_d, db1, Y_d, h1_d,
                                                edl_z, cur_z, zb1, Y_z, h1_z);
  // fused MLP 2+3 + pg
  {
    MlpP pd = {h1_d, w2t_d, db2, w3t_d, db3, pbuf_d, pg_d, Gtb, ND};
    MlpP pz = {h1_z, w2t_z, zb2, w3t_z, zb3, pbuf_z, pg_z, Gtb + HID*HID, NZ};
    k_mlp23<<<dim3(64, 1, 10), 256, 0, stream>>>(pd, pz, 5);
  }
  // metapath attention
  k_attn<<<ND + NZ, 64, 0, stream>>>(pbuf_d, pg_d, v2v, beta_d, out_d,
                                     pbuf_z, pg_z, beta_z, out_z);
  // decoder
  {
    GemmP pz = {out_z, wdect, bdec, Bbig, wsm, nullptr, 0, (long)NZ*HID, (long)NCH*HID, HID, HID, HID, NZ, 0};
    k_gemm<<<dim3(32, 2, 5), 256, 0, stream>>>(pz, pz, 5);
  }
  // final
  k_gemm_final<<<dim3(64, 32), 256, 0, stream>>>(out_d, Bbig, (float*)d_out);
}